// Round 13
// baseline (1146.213 us; speedup 1.0000x reference)
//
#include <hip/hip_runtime.h>
#include <hip/hip_bf16.h>

#define BATCH (1u<<20)
static constexpr float EPSBN = 1e-5f;
static constexpr float INV_B = 1.0f / (float)BATCH;

typedef unsigned int   uint;
typedef unsigned short ushort;

// f32 master table at ws+0, stride 132 floats, rows 0-65:
// 0-14 breed1(+b1) | 15-23 temp1 | 24-38 breed2 | 39-47 temp2
// 48-50 sz1 | 51-53 en1 | 54-56 sz2 | 57-59 en2 | 60-65 continuous
#define TSTR 132
#define NTABROWS 66
#define OFF_W2F    55296ULL            // W2^T A-frags bf16: 16*64*16B
#define OFF_W3F    71680ULL            // W3^T A-frags bf16: 4*64*16B
#define OFF_STATS  75776ULL            // 224 entries * 64B (sum @+0, sumsq @+32B)
#define OFF_PARAMS 90112ULL            // 448 f32 (fallback path only)
#define OFF_GRAM   94208ULL            // 67*67 f32 Gram (feature 66 = const-1)
#define OFF_X2     131072ULL           // bf16 [B][64] 128B rows; x3 aliased into first 64B
#define OFF_X3D    (131072ULL + 134217728ULL)   // dense bf16 [B][32] (tier 2)
#define T1_NEED    (131072ULL + 134217728ULL)
#define T2_NEED    (131072ULL + 134217728ULL + 67108864ULL)

struct Ptrs {
  const int *br1,*sz1,*en1,*tp1; const float *ag1,*so1,*wt1;
  const int *br2,*sz2,*en2,*tp2; const float *ag2,*so2,*wt2;
  const float *bemb,*temb;
  const float *W1,*b1,*g1,*be1;
  const float *W2,*b2,*g2,*be2;
  const float *W3,*b3,*g3,*be3;
  const float *W4,*b4;
  float* ws; float* out;
};

typedef __attribute__((ext_vector_type(8))) short bf16x8;
typedef __attribute__((ext_vector_type(4))) float f32x4;

__device__ __forceinline__ float4 ld4(const float* p) {
  return *reinterpret_cast<const float4*>(p);
}
__device__ __forceinline__ float4 f4add(float4 a, float4 b) {
  return make_float4(a.x+b.x, a.y+b.y, a.z+b.z, a.w+b.w);
}
__device__ __forceinline__ float4 f4fma(float4 a, float4 w, float s) {
  return make_float4(fmaf(w.x,s,a.x), fmaf(w.y,s,a.y), fmaf(w.z,s,a.z), fmaf(w.w,s,a.w));
}
__device__ __forceinline__ void add4(float4& a, const float4 b) {
  a.x += b.x; a.y += b.y; a.z += b.z; a.w += b.w;
}
__device__ __forceinline__ void fma4s(float4& a, const float4 b, float s) {
  a.x = fmaf(b.x, s, a.x); a.y = fmaf(b.y, s, a.y);
  a.z = fmaf(b.z, s, a.z); a.w = fmaf(b.w, s, a.w);
}

__device__ __forceinline__ ushort bfb(float f) {
  union { __hip_bfloat16 h; ushort u; } cv; cv.h = __float2bfloat16(f); return cv.u;
}
__device__ __forceinline__ uint pk2(float a, float b) {
  return ((uint)bfb(b) << 16) | (uint)bfb(a);
}
__device__ __forceinline__ bf16x8 ldfrag(const void* p) {
  union { uint4 u; bf16x8 v; } cv; cv.u = *reinterpret_cast<const uint4*>(p); return cv.v;
}
__device__ __forceinline__ bf16x8 mkfrag(uint a, uint b, uint c, uint d) {
  union { uint4 u; bf16x8 v; } cv; cv.u = make_uint4(a,b,c,d); return cv.v;
}
__device__ __forceinline__ float bflo(uint w) { return __uint_as_float(w << 16); }
__device__ __forceinline__ float bfhi(uint w) { return __uint_as_float(w & 0xffff0000u); }

struct SIdx { int r[8]; float v[6]; };
__device__ __forceinline__ SIdx load_idx(const Ptrs& P, unsigned s) {
  SIdx o;
  o.r[0] = P.br1[s];      o.r[1] = 15 + P.tp1[s];
  o.r[2] = 24 + P.br2[s]; o.r[3] = 39 + P.tp2[s];
  o.r[4] = 48 + P.sz1[s]; o.r[5] = 51 + P.en1[s];
  o.r[6] = 54 + P.sz2[s]; o.r[7] = 57 + P.en2[s];
  o.v[0] = P.ag1[s]*(1.0f/15.0f); o.v[1] = P.so1[s]; o.v[2] = P.wt1[s]*0.01f;
  o.v[3] = P.ag2[s]*(1.0f/15.0f); o.v[4] = P.so2[s]; o.v[5] = P.wt2[s]*0.01f;
  return o;
}

// tree-reassociated gather (fallback path)
__device__ __forceinline__ float4 gather4(const float* Tl, const float* contT,
                                          const int rb[8], const float v[6], int c) {
  float4 A = f4add(f4add(ld4(Tl+rb[0]+c), ld4(Tl+rb[1]+c)),
                   f4add(ld4(Tl+rb[2]+c), ld4(Tl+rb[3]+c)));
  float4 B = f4add(f4add(ld4(Tl+rb[4]+c), ld4(Tl+rb[5]+c)),
                   f4add(ld4(Tl+rb[6]+c), ld4(Tl+rb[7]+c)));
  A = f4fma(A, ld4(contT + 60*TSTR + c), v[0]);
  A = f4fma(A, ld4(contT + 61*TSTR + c), v[1]);
  A = f4fma(A, ld4(contT + 62*TSTR + c), v[2]);
  B = f4fma(B, ld4(contT + 63*TSTR + c), v[3]);
  B = f4fma(B, ld4(contT + 64*TSTR + c), v[4]);
  B = f4fma(B, ld4(contT + 65*TSTR + c), v[5]);
  return f4add(A, B);
}

__device__ __forceinline__ void load_rb(const Ptrs& P, unsigned s, int rb[8], float v[6]) {
  SIdx o = load_idx(P, s);
  #pragma unroll
  for (int i = 0; i < 8; ++i) rb[i] = o.r[i]*TSTR;
  #pragma unroll
  for (int i = 0; i < 6; ++i) v[i] = o.v[i];
}

__device__ __forceinline__ void stage_tab(const float* wsT, const float* params,
                                          float* Tl, bool bn1) {
  for (int i = threadIdx.x; i < NTABROWS*TSTR; i += blockDim.x) Tl[i] = wsT[i];
  if (bn1) {
    for (int i = threadIdx.x; i < 128; i += blockDim.x) {
      Tl[66*TSTR + i] = params[i];
      Tl[67*TSTR + i] = params[128 + i];
    }
  }
  __syncthreads();
}

__device__ __forceinline__ void x2_from_lds(const float* Tl, const int rb[8], const float v[6],
                                            const float* W2, const float* b2, float4 acc[16]) {
  #pragma unroll
  for (int j4 = 0; j4 < 16; ++j4) acc[j4] = ld4(b2 + j4*4);
  #pragma unroll 1
  for (int c4 = 0; c4 < 32; ++c4) {
    const int c = c4 * 4;
    float4 x = gather4(Tl, Tl, rb, v, c);
    const float4 sc = *reinterpret_cast<const float4*>(Tl + 66*TSTR + c);
    const float4 sh = *reinterpret_cast<const float4*>(Tl + 67*TSTR + c);
    float hv[4];
    hv[0] = fmaxf(fmaf(x.x, sc.x, sh.x), 0.0f);
    hv[1] = fmaxf(fmaf(x.y, sc.y, sh.y), 0.0f);
    hv[2] = fmaxf(fmaf(x.z, sc.z, sh.z), 0.0f);
    hv[3] = fmaxf(fmaf(x.w, sc.w, sh.w), 0.0f);
    #pragma unroll
    for (int r = 0; r < 4; ++r) {
      const float hr = hv[r];
      const float4* w = reinterpret_cast<const float4*>(W2 + (c + r)*64);
      #pragma unroll
      for (int j4 = 0; j4 < 16; ++j4) fma4s(acc[j4], w[j4], hr);
    }
  }
}

__device__ __forceinline__ void x3_from_acc2(const float4 acc2[16], const Ptrs& P,
                                             const float* sc2, const float* sh2,
                                             float4 acc3[8]) {
  #pragma unroll
  for (int j4 = 0; j4 < 8; ++j4) acc3[j4] = ld4(P.b3 + j4*4);
  #pragma unroll
  for (int k4 = 0; k4 < 16; ++k4) {
    const float4 a = acc2[k4];
    const float4 sc = ld4(sc2 + k4*4), sh = ld4(sh2 + k4*4);
    const float hr[4] = {
      fmaxf(fmaf(a.x, sc.x, sh.x), 0.0f),
      fmaxf(fmaf(a.y, sc.y, sh.y), 0.0f),
      fmaxf(fmaf(a.z, sc.z, sh.z), 0.0f),
      fmaxf(fmaf(a.w, sc.w, sh.w), 0.0f)};
    #pragma unroll
    for (int r = 0; r < 4; ++r) {
      const float4* w = reinterpret_cast<const float4*>(P.W3 + (k4*4 + r)*32);
      #pragma unroll
      for (int j4 = 0; j4 < 8; ++j4) fma4s(acc3[j4], w[j4], hr[r]);
    }
  }
}

__device__ __forceinline__ float bfly_tail32(float st[32], int lane) {
#define BSTEP(D) { const bool h = (lane & D) != 0; \
  _Pragma("unroll") \
  for (int i = 0; i < D; ++i) { \
    float mine = h ? st[i] : st[i+D]; \
    float oth  = __shfl_xor(mine, D, 64); \
    float keep = h ? st[i+D] : st[i]; \
    st[i] = keep + oth; } }
  BSTEP(16) BSTEP(8) BSTEP(4) BSTEP(2) BSTEP(1)
#undef BSTEP
  return st[0];
}

template<bool SQ>
__device__ __forceinline__ float bfly64_from(const float4 acc[16], int lane) {
  float st[32];
  const bool hi = (lane & 32) != 0;
  #pragma unroll
  for (int j4 = 0; j4 < 8; ++j4) {
#define DO1(comp, idx) { \
    float lo = acc[j4].comp, hc = acc[j4+8].comp; \
    if (SQ) { lo *= lo; hc *= hc; } \
    float mine = hi ? lo : hc; \
    float keep = hi ? hc : lo; \
    st[4*j4+idx] = keep + __shfl_xor(mine, 32, 64); }
    DO1(x,0) DO1(y,1) DO1(z,2) DO1(w,3)
#undef DO1
  }
  return bfly_tail32(st, lane);
}

template<bool SQ>
__device__ __forceinline__ float bfly32_from(const float4 acc3[8], int lane) {
  float st[32];
  const bool hi = (lane & 32) != 0;
  #pragma unroll
  for (int j4 = 0; j4 < 8; ++j4) {
#define DO1(comp, idx) { \
    float vv = acc3[j4].comp; \
    if (SQ) vv *= vv; \
    float mine = hi ? vv : 0.0f; \
    float keep = hi ? 0.0f : vv; \
    st[4*j4+idx] = keep + __shfl_xor(mine, 32, 64); }
    DO1(x,0) DO1(y,1) DO1(z,2) DO1(w,3)
#undef DO1
  }
  return bfly_tail32(st, lane);
}

// ---------------- kernels ----------------

__global__ __launch_bounds__(256) void k_prep(Ptrs P) {
  const int t = threadIdx.x;
  float* T = P.ws;
  {
    float* st = (float*)((char*)P.ws + OFF_STATS);
    for (int i = t; i < 224*16; i += 256) st[i] = 0.0f;
    float* G = (float*)((char*)P.ws + OFF_GRAM);
    for (int i = t; i < 67*67; i += 256) G[i] = 0.0f;
  }
  if (t < 128) {
    const int c = t;
    for (int b = 0; b < 15; ++b) {
      float a1 = P.b1[c], a2 = 0.0f;
      #pragma unroll
      for (int e = 0; e < 8; ++e) {
        a1 = fmaf(P.bemb[b*8+e], P.W1[e*128 + c], a1);
        a2 = fmaf(P.bemb[b*8+e], P.W1[(25+e)*128 + c], a2);
      }
      T[b*TSTR + c] = a1; T[(24+b)*TSTR + c] = a2;
    }
    for (int tt = 0; tt < 9; ++tt) {
      float a1 = 0.0f, a2 = 0.0f;
      #pragma unroll
      for (int e = 0; e < 8; ++e) {
        a1 = fmaf(P.temb[tt*8+e], P.W1[(14+e)*128 + c], a1);
        a2 = fmaf(P.temb[tt*8+e], P.W1[(39+e)*128 + c], a2);
      }
      T[(15+tt)*TSTR + c] = a1; T[(39+tt)*TSTR + c] = a2;
    }
    #pragma unroll
    for (int i = 0; i < 3; ++i) {
      T[(48+i)*TSTR + c] = P.W1[(8+i)*128 + c];
      T[(51+i)*TSTR + c] = P.W1[(11+i)*128 + c];
      T[(54+i)*TSTR + c] = P.W1[(33+i)*128 + c];
      T[(57+i)*TSTR + c] = P.W1[(36+i)*128 + c];
    }
    const int cr[6] = {22,23,24,47,48,49};
    #pragma unroll
    for (int m = 0; m < 6; ++m) T[(60+m)*TSTR + c] = P.W1[cr[m]*128 + c];
  }
  __syncthreads();
  __hip_bfloat16* w2f = (__hip_bfloat16*)((char*)P.ws + OFF_W2F);
  for (int slot = t; slot < 1024; slot += 256) {
    const int fid = slot >> 6, l = slot & 63;
    const int mt = fid >> 2, kk = fid & 3, q = l >> 4, m = l & 15;
    #pragma unroll
    for (int e = 0; e < 8; ++e)
      w2f[slot*8 + e] = __float2bfloat16(P.W2[(kk*32 + 8*q + e)*64 + 16*mt + m]);
  }
  __hip_bfloat16* w3f = (__hip_bfloat16*)((char*)P.ws + OFF_W3F);
  for (int slot = t; slot < 256; slot += 256) {
    const int fid = slot >> 6, l = slot & 63;
    const int mt = fid >> 1, kk = fid & 1, q = l >> 4, m = l & 15;
    #pragma unroll
    for (int e = 0; e < 8; ++e)
      w3f[slot*8 + e] = __float2bfloat16(P.W3[(kk*32 + 8*q + e)*32 + 16*mt + m]);
  }
}

// Feature Gram accumulation: 15 sparse features/sample
// (8 one-hot rows [strictly increasing indices] + 6 continuous [60..65] + const [66]).
// Variable-index pairs via LDS atomics; fixed-pair products in registers.
__global__ __launch_bounds__(256) void k_gram(Ptrs P) {
  __shared__ float Gl[67*67];
  for (int i = threadIdx.x; i < 67*67; i += 256) Gl[i] = 0.f;
  __syncthreads();
  float fx[28];
  #pragma unroll
  for (int i = 0; i < 28; ++i) fx[i] = 0.f;
  const unsigned gid = blockIdx.x*256 + threadIdx.x;
  const unsigned nth = gridDim.x*256;
  for (unsigned s = gid; s < BATCH; s += nth) {
    const SIdx o = load_idx(P, s);
    #pragma unroll
    for (int a = 0; a < 8; ++a) {
      const int ra = o.r[a]*67;
      #pragma unroll
      for (int b = a; b < 8; ++b) atomicAdd(&Gl[ra + o.r[b]], 1.0f);
      #pragma unroll
      for (int m = 0; m < 6; ++m) atomicAdd(&Gl[ra + 60 + m], o.v[m]);
      atomicAdd(&Gl[ra + 66], 1.0f);
    }
    int p = 0;
    #pragma unroll
    for (int m = 0; m < 6; ++m)
      #pragma unroll
      for (int n = m; n < 6; ++n) { fx[p] = fmaf(o.v[m], o.v[n], fx[p]); ++p; }
    #pragma unroll
    for (int m = 0; m < 6; ++m) fx[21+m] += o.v[m];
    fx[27] += 1.0f;
  }
  {
    int p = 0;
    #pragma unroll
    for (int m = 0; m < 6; ++m)
      #pragma unroll
      for (int n = m; n < 6; ++n) { atomicAdd(&Gl[(60+m)*67 + 60+n], fx[p]); ++p; }
    #pragma unroll
    for (int m = 0; m < 6; ++m) atomicAdd(&Gl[(60+m)*67 + 66], fx[21+m]);
    atomicAdd(&Gl[66*67 + 66], fx[27]);
  }
  __syncthreads();
  float* G = (float*)((char*)P.ws + OFF_GRAM);
  for (int i = threadIdx.x; i < 67*67; i += 256) {
    const float g = Gl[i];
    if (g != 0.f) atomicAdd(&G[i], g);
  }
}

// Analytic BN1 stats from Gram: sum_c = sum_i G[i][66] T_i[c];
// sumsq_c = sum_i T_i (G[i][i] T_i + 2 sum_{j>i} G[i][j] T_j).
__global__ __launch_bounds__(128) void k_bn1fin(Ptrs P) {
  __shared__ float Gl[67*67];
  const float* G = (const float*)((const char*)P.ws + OFF_GRAM);
  for (int i = threadIdx.x; i < 67*67; i += 128) Gl[i] = G[i];
  __syncthreads();
  const int c = threadIdx.x;
  float sum = 0.f, sq = 0.f;
  #pragma unroll 1
  for (int i = 0; i < 66; ++i) {
    const float ti = P.ws[i*TSTR + c];
    sum = fmaf(Gl[i*67 + 66], ti, sum);
    float acc = Gl[i*67 + i] * ti;
    #pragma unroll 1
    for (int j = i + 1; j < 66; ++j)
      acc = fmaf(2.0f*Gl[i*67 + j], P.ws[j*TSTR + c], acc);
    sq = fmaf(acc, ti, sq);
  }
  float* stat = (float*)((char*)P.ws + OFF_STATS) + (size_t)c*16;
  stat[0] = sum; stat[8] = sq;
}

// BN1 stats by direct encode (FALLBACK path only)
__global__ __launch_bounds__(512) void k_stats1(Ptrs P) {
  __shared__ __align__(16) float Tl[60*TSTR];
  __shared__ float sred[256];
  for (int i = threadIdx.x; i < 60*TSTR; i += 512) Tl[i] = P.ws[i];
  if (threadIdx.x < 256) sred[threadIdx.x] = 0.f;
  __syncthreads();
  const int lane = threadIdx.x & 63;
  const int q = lane >> 4, m16 = lane & 15;
  const float* contT = P.ws;
  const unsigned gw = (blockIdx.x*512 + threadIdx.x) >> 6;
  const unsigned nw = (gridDim.x*512) >> 6;
  const int kk = gw & 3;
  const int c = kk*32 + 8*q;
  const unsigned NT = BATCH >> 4;
  unsigned it = gw >> 2;
  const unsigned ts = nw >> 2;
  float4 sa = make_float4(0,0,0,0), sb = sa, qa = sa, qb = sa;
  bool active = it < NT;
  int rb[8]; float v[6];
  if (active) load_rb(P, it*16 + m16, rb, v);
  while (active) {
    const unsigned itn = it + ts;
    const bool more = itn < NT;
    int rbn[8]; float vn[6];
    if (more) load_rb(P, itn*16 + m16, rbn, vn);
    const float4 xa = gather4(Tl, contT, rb, v, c);
    const float4 xb = gather4(Tl, contT, rb, v, c + 4);
    add4(sa, xa); add4(sb, xb);
    qa.x = fmaf(xa.x, xa.x, qa.x); qa.y = fmaf(xa.y, xa.y, qa.y);
    qa.z = fmaf(xa.z, xa.z, qa.z); qa.w = fmaf(xa.w, xa.w, qa.w);
    qb.x = fmaf(xb.x, xb.x, qb.x); qb.y = fmaf(xb.y, xb.y, qb.y);
    qb.z = fmaf(xb.z, xb.z, qb.z); qb.w = fmaf(xb.w, xb.w, qb.w);
    if (!more) break;
    #pragma unroll
    for (int i = 0; i < 8; ++i) rb[i] = rbn[i];
    #pragma unroll
    for (int i = 0; i < 6; ++i) v[i] = vn[i];
    it = itn;
  }
  #pragma unroll
  for (int d = 1; d <= 8; d <<= 1) {
    sa.x += __shfl_xor(sa.x, d, 64); sa.y += __shfl_xor(sa.y, d, 64);
    sa.z += __shfl_xor(sa.z, d, 64); sa.w += __shfl_xor(sa.w, d, 64);
    sb.x += __shfl_xor(sb.x, d, 64); sb.y += __shfl_xor(sb.y, d, 64);
    sb.z += __shfl_xor(sb.z, d, 64); sb.w += __shfl_xor(sb.w, d, 64);
    qa.x += __shfl_xor(qa.x, d, 64); qa.y += __shfl_xor(qa.y, d, 64);
    qa.z += __shfl_xor(qa.z, d, 64); qa.w += __shfl_xor(qa.w, d, 64);
    qb.x += __shfl_xor(qb.x, d, 64); qb.y += __shfl_xor(qb.y, d, 64);
    qb.z += __shfl_xor(qb.z, d, 64); qb.w += __shfl_xor(qb.w, d, 64);
  }
  if (m16 == 0) {
    atomicAdd(&sred[c+0], sa.x); atomicAdd(&sred[c+1], sa.y);
    atomicAdd(&sred[c+2], sa.z); atomicAdd(&sred[c+3], sa.w);
    atomicAdd(&sred[c+4], sb.x); atomicAdd(&sred[c+5], sb.y);
    atomicAdd(&sred[c+6], sb.z); atomicAdd(&sred[c+7], sb.w);
    atomicAdd(&sred[128+c+0], qa.x); atomicAdd(&sred[128+c+1], qa.y);
    atomicAdd(&sred[128+c+2], qa.z); atomicAdd(&sred[128+c+3], qa.w);
    atomicAdd(&sred[128+c+4], qb.x); atomicAdd(&sred[128+c+5], qb.y);
    atomicAdd(&sred[128+c+6], qb.z); atomicAdd(&sred[128+c+7], qb.w);
  }
  __syncthreads();
  if (threadIdx.x < 128) {
    float* stat = (float*)((char*)P.ws + OFF_STATS) + (size_t)threadIdx.x*16;
    atomicAdd(stat,     sred[threadIdx.x]);
    atomicAdd(stat + 8, sred[128+threadIdx.x]);
  }
}

// fallback-path finalize
__global__ void k_finalize(Ptrs P, int nch, int entry0, int pofs,
                           const float* g, const float* be) {
  const int c = threadIdx.x;
  if (c >= nch) return;
  const float* stat = (const float*)((const char*)P.ws + OFF_STATS) + (size_t)(entry0 + c)*16;
  const float mean = stat[0] * INV_B;
  const float var  = stat[8] * INV_B - mean*mean;
  const float inv  = 1.0f / sqrtf(var + EPSBN);
  const float scale = g[c] * inv;
  float* params = (float*)((char*)P.ws + OFF_PARAMS);
  params[pofs + c]       = scale;
  params[pofs + nch + c] = be[c] - mean * scale;
}

// Layer2 MFMA, LEAN (round-9 proven): in-kernel BN1 finalize into LDS bn[].
__global__ __launch_bounds__(512) void k_l2m(Ptrs P) {
  __shared__ __align__(16) float Tl[60*TSTR];
  __shared__ __align__(16) float bn[256];   // sc1[0..127], sh1[128..255]
  for (int i = threadIdx.x; i < 60*TSTR; i += 512) Tl[i] = P.ws[i];
  if (threadIdx.x < 128) {
    const float* stat = (const float*)((const char*)P.ws + OFF_STATS) + (size_t)threadIdx.x*16;
    const float mean = stat[0] * INV_B;
    const float var  = stat[8] * INV_B - mean*mean;
    const float scale = P.g1[threadIdx.x] / sqrtf(var + EPSBN);
    bn[threadIdx.x]       = scale;
    bn[128 + threadIdx.x] = P.be1[threadIdx.x] - mean * scale;
  }
  __syncthreads();
  const float* contT = P.ws;
  const int lane = threadIdx.x & 63;
  const int q = lane >> 4, m16 = lane & 15;
  const char* w2fB = (const char*)P.ws + OFF_W2F;
  char* x2B = (char*)P.ws + OFF_X2;
  const unsigned nw = (gridDim.x*512) >> 6;
  const unsigned NT = BATCH >> 4;
  unsigned it = (blockIdx.x*512 + threadIdx.x) >> 6;
  if (it >= NT) return;
  SIdx cur = load_idx(P, it*16 + m16);
  while (true) {
    const unsigned itn = it + nw;
    const bool more = itn < NT;
    SIdx nxt;
    if (more) nxt = load_idx(P, itn*16 + m16);   // prefetch next tile's indices
    const unsigned s = it*16 + m16;
    int rb[8];
    #pragma unroll
    for (int i = 0; i < 8; ++i) rb[i] = cur.r[i]*TSTR;
    f32x4 D[4];
    #pragma unroll
    for (int mt = 0; mt < 4; ++mt) {
      const float4 b = ld4(P.b2 + 16*mt + 4*q);
      D[mt][0] = b.x; D[mt][1] = b.y; D[mt][2] = b.z; D[mt][3] = b.w;
    }
    #pragma unroll
    for (int kk = 0; kk < 4; ++kk) {
      const int c = kk*32 + 8*q;
      const float4 xa = gather4(Tl, contT, rb, cur.v, c);
      const float4 xb = gather4(Tl, contT, rb, cur.v, c + 4);
      const float4 sca = ld4(bn + c), sha = ld4(bn + 128 + c);
      const float4 scb = ld4(bn + c + 4), shb = ld4(bn + 128 + c + 4);
      const float h0 = fmaxf(fmaf(xa.x, sca.x, sha.x), 0.f);
      const float h1 = fmaxf(fmaf(xa.y, sca.y, sha.y), 0.f);
      const float h2 = fmaxf(fmaf(xa.z, sca.z, sha.z), 0.f);
      const float h3 = fmaxf(fmaf(xa.w, sca.w, sha.w), 0.f);
      const float h4 = fmaxf(fmaf(xb.x, scb.x, shb.x), 0.f);
      const float h5 = fmaxf(fmaf(xb.y, scb.y, shb.y), 0.f);
      const float h6 = fmaxf(fmaf(xb.z, scb.z, shb.z), 0.f);
      const float h7 = fmaxf(fmaf(xb.w, scb.w, shb.w), 0.f);
      const bf16x8 bf = mkfrag(pk2(h0,h1), pk2(h2,h3), pk2(h4,h5), pk2(h6,h7));
      #pragma unroll
      for (int mt = 0; mt < 4; ++mt) {
        const bf16x8 af = ldfrag(w2fB + (size_t)((mt*4+kk)*64 + lane)*16);
        D[mt] = __builtin_amdgcn_mfma_f32_16x16x32_bf16(af, bf, D[mt], 0, 0, 0);
      }
    }
    #pragma unroll
    for (int mt = 0; mt < 4; ++mt) {
      const uint lo = pk2(D[mt][0], D[mt][1]);
      const uint hi = pk2(D[mt][2], D[mt][3]);
      *reinterpret_cast<uint2*>(x2B + (size_t)s*128 + (16*mt + 4*q)*2) = make_uint2(lo, hi);
    }
    if (!more) break;
    cur = nxt; it = itn;
  }
}

// BN2 stats from stored bf16 x2 (round-9)
__global__ __launch_bounds__(256) void k_stats2(Ptrs P) {
  const uint* x2u = (const uint*)((const char*)P.ws + OFF_X2);
  const int pid = threadIdx.x & 31;
  const int lane = threadIdx.x & 63;
  const int w = threadIdx.x >> 6;
  float slo = 0.f, shi = 0.f, qlo = 0.f, qhi = 0.f;
  const unsigned r0 = blockIdx.x*8 + (threadIdx.x >> 5);
  const unsigned rs = gridDim.x*8;
  #pragma unroll 4
  for (unsigned r = r0; r < BATCH; r += rs) {
    const uint u = x2u[(size_t)r*32 + pid];
    const float lo = bflo(u), hi = bfhi(u);
    slo += lo; shi += hi;
    qlo = fmaf(lo, lo, qlo); qhi = fmaf(hi, hi, qhi);
  }
  slo += __shfl_xor(slo, 32, 64); shi += __shfl_xor(shi, 32, 64);
  qlo += __shfl_xor(qlo, 32, 64); qhi += __shfl_xor(qhi, 32, 64);
  __shared__ float red[512];
  if (lane < 32) {
    red[w*64 + 2*pid]       = slo; red[w*64 + 2*pid + 1]       = shi;
    red[256 + w*64 + 2*pid] = qlo; red[256 + w*64 + 2*pid + 1] = qhi;
  }
  __syncthreads();
  if (threadIdx.x < 64) {
    const int c = threadIdx.x;
    const float s  = red[c] + red[64+c] + red[128+c] + red[192+c];
    const float qq = red[256+c] + red[320+c] + red[384+c] + red[448+c];
    float* stat = (float*)((char*)P.ws + OFF_STATS) + (size_t)(128 + c)*16;
    atomicAdd(stat, s); atomicAdd(stat + 8, qq);
  }
}

// Layer3 MFMA (round-9): in-kernel BN2 finalize; x2 prefetch; optional dense x3
__global__ __launch_bounds__(256) void k_l3m(Ptrs P, int dense) {
  __shared__ __align__(16) float bn[128];
  if (threadIdx.x < 64) {
    const float* stat = (const float*)((const char*)P.ws + OFF_STATS) + (size_t)(128 + threadIdx.x)*16;
    const float mean = stat[0] * INV_B;
    const float var  = stat[8] * INV_B - mean*mean;
    const float scale = P.g2[threadIdx.x] / sqrtf(var + EPSBN);
    bn[threadIdx.x]      = scale;
    bn[64 + threadIdx.x] = P.be2[threadIdx.x] - mean * scale;
  }
  __syncthreads();
  const int lane = threadIdx.x & 63;
  const int q = lane >> 4, m16 = lane & 15;
  const char* w3fB = (const char*)P.ws + OFF_W3F;
  const char* xB = (const char*)P.ws + OFF_X2;
  char* x3B = dense ? ((char*)P.ws + OFF_X3D) : ((char*)P.ws + OFF_X2);
  const size_t x3str = dense ? 64 : 128;
  const unsigned nw = (gridDim.x*256) >> 6;
  const unsigned NT = BATCH >> 4;
  unsigned it = (blockIdx.x*256 + threadIdx.x) >> 6;
  if (it >= NT) return;
  unsigned s = it*16 + m16;
  uint4 u0 = *reinterpret_cast<const uint4*>(xB + (size_t)s*128 + q*16);
  uint4 u1 = *reinterpret_cast<const uint4*>(xB + (size_t)s*128 + 64 + q*16);
  while (true) {
    const unsigned itn = it + nw;
    const bool more = itn < NT;
    uint4 n0, n1;
    if (more) {
      const unsigned sn = itn*16 + m16;
      n0 = *reinterpret_cast<const uint4*>(xB + (size_t)sn*128 + q*16);
      n1 = *reinterpret_cast<const uint4*>(xB + (size_t)sn*128 + 64 + q*16);
    }
    f32x4 D[2];
    #pragma unroll
    for (int mt = 0; mt < 2; ++mt) {
      const float4 b = ld4(P.b3 + 16*mt + 4*q);
      D[mt][0] = b.x; D[mt][1] = b.y; D[mt][2] = b.z; D[mt][3] = b.w;
    }
    #pragma unroll
    for (int kk = 0; kk < 2; ++kk) {
      const uint4 u = (kk == 0) ? u0 : u1;
      const int c = kk*32 + 8*q;
      const float4 scA = ld4(bn + c), shA = ld4(bn + 64 + c);
      const float4 scB = ld4(bn + c + 4), shB = ld4(bn + 64 + c + 4);
      const uint w[4] = {u.x,u.y,u.z,u.w};
      const float h0 = fmaxf(fmaf(bflo(w[0]), scA.x, shA.x), 0.f);
      const float h1 = fmaxf(fmaf(bfhi(w[0]), scA.y, shA.y), 0.f);
      const float h2 = fmaxf(fmaf(bflo(w[1]), scA.z, shA.z), 0.f);
      const float h3 = fmaxf(fmaf(bfhi(w[1]), scA.w, shA.w), 0.f);
      const float h4 = fmaxf(fmaf(bflo(w[2]), scB.x, shB.x), 0.f);
      const float h5 = fmaxf(fmaf(bfhi(w[2]), scB.y, shB.y), 0.f);
      const float h6 = fmaxf(fmaf(bflo(w[3]), scB.z, shB.z), 0.f);
      const float h7 = fmaxf(fmaf(bfhi(w[3]), scB.w, shB.w), 0.f);
      const bf16x8 bf = mkfrag(pk2(h0,h1), pk2(h2,h3), pk2(h4,h5), pk2(h6,h7));
      #pragma unroll
      for (int mt = 0; mt < 2; ++mt) {
        const bf16x8 af = ldfrag(w3fB + (size_t)((mt*2+kk)*64 + lane)*16);
        D[mt] = __builtin_amdgcn_mfma_f32_16x16x32_bf16(af, bf, D[mt], 0, 0, 0);
      }
    }
    #pragma unroll
    for (int mt = 0; mt < 2; ++mt) {
      const uint lo = pk2(D[mt][0], D[mt][1]);
      const uint hi = pk2(D[mt][2], D[mt][3]);
      *reinterpret_cast<uint2*>(x3B + (size_t)s*x3str + (16*mt + 4*q)*2) = make_uint2(lo, hi);
    }
    if (!more) break;
    u0 = n0; u1 = n1; it = itn; s = it*16 + m16;
  }
}

// BN3 stats (round-9)
__global__ __launch_bounds__(256) void k_stats3(Ptrs P, int dense) {
  const uint* xu = dense ? (const uint*)((const char*)P.ws + OFF_X3D)
                         : (const uint*)((const char*)P.ws + OFF_X2);
  const unsigned rstr = dense ? 16 : 32;
  const int pid = threadIdx.x & 15;
  const int lane = threadIdx.x & 63;
  const int w = threadIdx.x >> 6;
  float slo = 0.f, shi = 0.f, qlo = 0.f, qhi = 0.f;
  const unsigned r0 = blockIdx.x*16 + (threadIdx.x >> 4);
  const unsigned rs = gridDim.x*16;
  #pragma unroll 4
  for (unsigned r = r0; r < BATCH; r += rs) {
    const uint u = xu[(size_t)r*rstr + pid];
    const float lo = bflo(u), hi = bfhi(u);
    slo += lo; shi += hi;
    qlo = fmaf(lo, lo, qlo); qhi = fmaf(hi, hi, qhi);
  }
  #pragma unroll
  for (int d = 16; d <= 32; d <<= 1) {
    slo += __shfl_xor(slo, d, 64); shi += __shfl_xor(shi, d, 64);
    qlo += __shfl_xor(qlo, d, 64); qhi += __shfl_xor(qhi, d, 64);
  }
  __shared__ float red[256];
  if (lane < 16) {
    red[w*32 + 2*pid]       = slo; red[w*32 + 2*pid + 1]       = shi;
    red[128 + w*32 + 2*pid] = qlo; red[128 + w*32 + 2*pid + 1] = qhi;
  }
  __syncthreads();
  if (threadIdx.x < 32) {
    const int c = threadIdx.x;
    const float s  = red[c] + red[32+c] + red[64+c] + red[96+c];
    const float qq = red[128+c] + red[160+c] + red[192+c] + red[224+c];
    float* stat = (float*)((char*)P.ws + OFF_STATS) + (size_t)(192 + c)*16;
    atomicAdd(stat, s); atomicAdd(stat + 8, qq);
  }
}

// Layer4 (round-9)
__global__ __launch_bounds__(256) void k_l4n(Ptrs P, int dense) {
  __shared__ float bn[64];
  if (threadIdx.x < 32) {
    const float* stat = (const float*)((const char*)P.ws + OFF_STATS) + (size_t)(192 + threadIdx.x)*16;
    const float mean = stat[0] * INV_B;
    const float var  = stat[8] * INV_B - mean*mean;
    const float scale = P.g3[threadIdx.x] / sqrtf(var + EPSBN);
    bn[threadIdx.x]      = scale;
    bn[32 + threadIdx.x] = P.be3[threadIdx.x] - mean * scale;
  }
  __syncthreads();
  const float* sc3 = bn, *sh3 = bn + 32;
  const char* xB = dense ? ((const char*)P.ws + OFF_X3D) : ((const char*)P.ws + OFF_X2);
  const size_t xstr = dense ? 64 : 128;
  const unsigned stride = gridDim.x * 256;
  for (unsigned s = blockIdx.x*256 + threadIdx.x; s < BATCH; s += stride) {
    float z = P.b4[0];
    #pragma unroll
    for (int c16 = 0; c16 < 4; ++c16) {
      const uint4 u = *reinterpret_cast<const uint4*>(xB + (size_t)s*xstr + c16*16);
      const uint w[4] = {u.x,u.y,u.z,u.w};
      #pragma unroll
      for (int j = 0; j < 4; ++j) {
        const int ch = c16*8 + 2*j;
        const float hlo = fmaxf(fmaf(bflo(w[j]), sc3[ch],   sh3[ch]),   0.f);
        const float hhi = fmaxf(fmaf(bfhi(w[j]), sc3[ch+1], sh3[ch+1]), 0.f);
        z = fmaf(hlo, P.W4[ch], z);
        z = fmaf(hhi, P.W4[ch+1], z);
      }
    }
    P.out[s] = 1.0f / (1.0f + __expf(-z));
  }
}

// -------- fallback (small ws): recompute path (round-9) --------
__global__ __launch_bounds__(256) void k_l2r(Ptrs P) {
  __shared__ __align__(16) float Tl[68*TSTR];
  __shared__ float red[512];
  const float* params = (const float*)((const char*)P.ws + OFF_PARAMS);
  stage_tab(P.ws, params, Tl, true);
  const int lane = threadIdx.x & 63;
  float4 sums[16], sqs[16];
  #pragma unroll
  for (int j4 = 0; j4 < 16; ++j4) {
    sums[j4] = make_float4(0.f,0.f,0.f,0.f);
    sqs[j4]  = make_float4(0.f,0.f,0.f,0.f);
  }
  const unsigned stride = gridDim.x * 256;
  for (unsigned s = blockIdx.x*256 + threadIdx.x; s < BATCH; s += stride) {
    int rb[8]; float v[6];
    load_rb(P, s, rb, v);
    float4 acc[16];
    x2_from_lds(Tl, rb, v, P.W2, P.b2, acc);
    #pragma unroll
    for (int j4 = 0; j4 < 16; ++j4) {
      add4(sums[j4], acc[j4]);
      sqs[j4].x = fmaf(acc[j4].x, acc[j4].x, sqs[j4].x);
      sqs[j4].y = fmaf(acc[j4].y, acc[j4].y, sqs[j4].y);
      sqs[j4].z = fmaf(acc[j4].z, acc[j4].z, sqs[j4].z);
      sqs[j4].w = fmaf(acc[j4].w, acc[j4].w, sqs[j4].w);
    }
  }
  const float psum = bfly64_from<false>(sums, lane);
  const float psq  = bfly64_from<false>(sqs,  lane);
  red[threadIdx.x] = psum; red[256 + threadIdx.x] = psq;
  __syncthreads();
  const int t = threadIdx.x;
  if (t < 64) {
    const float s0 = red[t] + red[t+64] + red[t+128] + red[t+192];
    const float q0 = red[256+t] + red[256+t+64] + red[256+t+128] + red[256+t+192];
    float* stat = (float*)((char*)P.ws + OFF_STATS) + (size_t)(128 + t)*16;
    atomicAdd(stat, s0); atomicAdd(stat + 8, q0);
  }
}

__global__ __launch_bounds__(256) void k_l3_rec(Ptrs P) {
  __shared__ __align__(16) float Tl[68*TSTR];
  __shared__ float red[512];
  const float* params = (const float*)((const char*)P.ws + OFF_PARAMS);
  stage_tab(P.ws, params, Tl, true);
  const float* sc2 = params + 256, *sh2 = params + 320;
  const int lane = threadIdx.x & 63;
  float4 sums3[8], sqs3[8];
  #pragma unroll
  for (int j4 = 0; j4 < 8; ++j4) {
    sums3[j4] = make_float4(0.f,0.f,0.f,0.f);
    sqs3[j4]  = make_float4(0.f,0.f,0.f,0.f);
  }
  const unsigned stride = gridDim.x * 256;
  for (unsigned s = blockIdx.x*256 + threadIdx.x; s < BATCH; s += stride) {
    int rb[8]; float v[6];
    load_rb(P, s, rb, v);
    float4 acc2[16];
    x2_from_lds(Tl, rb, v, P.W2, P.b2, acc2);
    float4 acc3[8];
    x3_from_acc2(acc2, P, sc2, sh2, acc3);
    #pragma unroll
    for (int j4 = 0; j4 < 8; ++j4) {
      add4(sums3[j4], acc3[j4]);
      sqs3[j4].x = fmaf(acc3[j4].x, acc3[j4].x, sqs3[j4].x);
      sqs3[j4].y = fmaf(acc3[j4].y, acc3[j4].y, sqs3[j4].y);
      sqs3[j4].z = fmaf(acc3[j4].z, acc3[j4].z, sqs3[j4].z);
      sqs3[j4].w = fmaf(acc3[j4].w, acc3[j4].w, sqs3[j4].w);
    }
  }
  const float psum = bfly32_from<false>(sums3, lane);
  const float psq  = bfly32_from<false>(sqs3,  lane);
  red[threadIdx.x] = psum; red[256 + threadIdx.x] = psq;
  __syncthreads();
  const int t = threadIdx.x;
  if (t < 32) {
    const float s0 = red[t] + red[t+64] + red[t+128] + red[t+192];
    const float q0 = red[256+t] + red[256+t+64] + red[256+t+128] + red[256+t+192];
    float* stat = (float*)((char*)P.ws + OFF_STATS) + (size_t)(192 + t)*16;
    atomicAdd(stat, s0); atomicAdd(stat + 8, q0);
  }
}

__global__ __launch_bounds__(256) void k_l4_rec(Ptrs P) {
  __shared__ __align__(16) float Tl[68*TSTR];
  const float* params = (const float*)((const char*)P.ws + OFF_PARAMS);
  stage_tab(P.ws, params, Tl, true);
  const float* sc2 = params + 256, *sh2 = params + 320;
  const float* sc3 = params + 384, *sh3 = params + 416;
  const unsigned stride = gridDim.x * 256;
  for (unsigned s = blockIdx.x*256 + threadIdx.x; s < BATCH; s += stride) {
    int rb[8]; float v[6];
    load_rb(P, s, rb, v);
    float4 acc2[16];
    x2_from_lds(Tl, rb, v, P.W2, P.b2, acc2);
    float4 acc3[8];
    x3_from_acc2(acc2, P, sc2, sh2, acc3);
    float z = P.b4[0];
    #pragma unroll
    for (int k4 = 0; k4 < 8; ++k4) {
      const float4 a = acc3[k4];
      const float4 sc = ld4(sc3 + k4*4), sh = ld4(sh3 + k4*4);
      z = fmaf(fmaxf(fmaf(a.x, sc.x, sh.x), 0.0f), P.W4[k4*4+0], z);
      z = fmaf(fmaxf(fmaf(a.y, sc.y, sh.y), 0.0f), P.W4[k4*4+1], z);
      z = fmaf(fmaxf(fmaf(a.z, sc.z, sh.z), 0.0f), P.W4[k4*4+2], z);
      z = fmaf(fmaxf(fmaf(a.w, sc.w, sh.w), 0.0f), P.W4[k4*4+3], z);
    }
    P.out[s] = 1.0f / (1.0f + __expf(-z));
  }
}

// ---------------- host ----------------

extern "C" void kernel_launch(void* const* d_in, const int* in_sizes, int n_in,
                              void* d_out, int out_size, void* d_ws, size_t ws_size,
                              hipStream_t stream) {
  Ptrs P;
  P.br1 = (const int*)d_in[0];  P.sz1 = (const int*)d_in[1];
  P.en1 = (const int*)d_in[2];  P.tp1 = (const int*)d_in[3];
  P.ag1 = (const float*)d_in[4]; P.so1 = (const float*)d_in[5]; P.wt1 = (const float*)d_in[6];
  P.br2 = (const int*)d_in[7];  P.sz2 = (const int*)d_in[8];
  P.en2 = (const int*)d_in[9];  P.tp2 = (const int*)d_in[10];
  P.ag2 = (const float*)d_in[11]; P.so2 = (const float*)d_in[12]; P.wt2 = (const float*)d_in[13];
  P.bemb = (const float*)d_in[14]; P.temb = (const float*)d_in[15];
  P.W1 = (const float*)d_in[16]; P.b1 = (const float*)d_in[17];
  P.g1 = (const float*)d_in[18]; P.be1 = (const float*)d_in[19];
  P.W2 = (const float*)d_in[20]; P.b2 = (const float*)d_in[21];
  P.g2 = (const float*)d_in[22]; P.be2 = (const float*)d_in[23];
  P.W3 = (const float*)d_in[24]; P.b3 = (const float*)d_in[25];
  P.g3 = (const float*)d_in[26]; P.be3 = (const float*)d_in[27];
  P.W4 = (const float*)d_in[28]; P.b4 = (const float*)d_in[29];
  P.ws = (float*)d_ws; P.out = (float*)d_out;

  const bool t1 = ws_size >= T1_NEED;
  const int dense = (ws_size >= T2_NEED) ? 1 : 0;

  hipLaunchKernelGGL(k_prep, dim3(1), dim3(256), 0, stream, P);
  if (t1) {
    hipLaunchKernelGGL(k_gram, dim3(512), dim3(256), 0, stream, P);
    hipLaunchKernelGGL(k_bn1fin, dim3(1), dim3(128), 0, stream, P);
    hipLaunchKernelGGL(k_l2m, dim3(1024), dim3(512), 0, stream, P);
    hipLaunchKernelGGL(k_stats2, dim3(1024), dim3(256), 0, stream, P);
    hipLaunchKernelGGL(k_l3m, dim3(2048), dim3(256), 0, stream, P, dense);
    hipLaunchKernelGGL(k_stats3, dim3(1024), dim3(256), 0, stream, P, dense);
    hipLaunchKernelGGL(k_l4n, dim3(2048), dim3(256), 0, stream, P, dense);
  } else {
    hipLaunchKernelGGL(k_stats1, dim3(1024), dim3(512), 0, stream, P);
    hipLaunchKernelGGL(k_finalize, dim3(1), dim3(128), 0, stream, P, 128, 0, 0, P.g1, P.be1);
    hipLaunchKernelGGL(k_l2r, dim3(1024), dim3(256), 0, stream, P);
    hipLaunchKernelGGL(k_finalize, dim3(1), dim3(64), 0, stream, P, 64, 128, 256, P.g2, P.be2);
    hipLaunchKernelGGL(k_l3_rec, dim3(1024), dim3(256), 0, stream, P);
    hipLaunchKernelGGL(k_finalize, dim3(1), dim3(32), 0, stream, P, 32, 192, 384, P.g3, P.be3);
    hipLaunchKernelGGL(k_l4_rec, dim3(2048), dim3(256), 0, stream, P);
  }
}

// Round 14
// 664.522 us; speedup vs baseline: 1.7249x; 1.7249x over previous
//
#include <hip/hip_runtime.h>
#include <hip/hip_bf16.h>

#define BATCH (1u<<20)
static constexpr float EPSBN = 1e-5f;
static constexpr float INV_B = 1.0f / (float)BATCH;

typedef unsigned int   uint;
typedef unsigned short ushort;

// f32 master table at ws+0, stride 132 floats, rows 0-65:
// 0-14 breed1(+b1) | 15-23 temp1 | 24-38 breed2 | 39-47 temp2
// 48-50 sz1 | 51-53 en1 | 54-56 sz2 | 57-59 en2 | 60-65 continuous
#define TSTR 132
#define NTABROWS 66
#define OFF_W2F    55296ULL            // W2^T A-frags bf16: 16*64*16B
#define OFF_W3F    71680ULL            // W3^T A-frags bf16: 4*64*16B
#define OFF_STATS  75776ULL            // 224 entries * 64B (sum @+0, sumsq @+32B)
#define OFF_PARAMS 90112ULL            // 448 f32 (fallback path only)
#define OFF_W1S    94208ULL            // RAW T^T A-frags hi/lo: 48 frag * 1KB = 48KB
#define OFF_X2     147456ULL           // bf16 [B][64] 128B rows; x3 aliased into first 64B
#define OFF_X3D    (147456ULL + 134217728ULL)   // dense bf16 [B][32] (tier 2)
#define T1_NEED    (147456ULL + 134217728ULL)
#define T2_NEED    (147456ULL + 134217728ULL + 67108864ULL)

struct Ptrs {
  const int *br1,*sz1,*en1,*tp1; const float *ag1,*so1,*wt1;
  const int *br2,*sz2,*en2,*tp2; const float *ag2,*so2,*wt2;
  const float *bemb,*temb;
  const float *W1,*b1,*g1,*be1;
  const float *W2,*b2,*g2,*be2;
  const float *W3,*b3,*g3,*be3;
  const float *W4,*b4;
  float* ws; float* out;
};

typedef __attribute__((ext_vector_type(8))) short bf16x8;
typedef __attribute__((ext_vector_type(4))) float f32x4;

__device__ __forceinline__ float4 ld4(const float* p) {
  return *reinterpret_cast<const float4*>(p);
}
__device__ __forceinline__ float4 f4add(float4 a, float4 b) {
  return make_float4(a.x+b.x, a.y+b.y, a.z+b.z, a.w+b.w);
}
__device__ __forceinline__ float4 f4fma(float4 a, float4 w, float s) {
  return make_float4(fmaf(w.x,s,a.x), fmaf(w.y,s,a.y), fmaf(w.z,s,a.z), fmaf(w.w,s,a.w));
}
__device__ __forceinline__ void add4(float4& a, const float4 b) {
  a.x += b.x; a.y += b.y; a.z += b.z; a.w += b.w;
}
__device__ __forceinline__ void fma4s(float4& a, const float4 b, float s) {
  a.x = fmaf(b.x, s, a.x); a.y = fmaf(b.y, s, a.y);
  a.z = fmaf(b.z, s, a.z); a.w = fmaf(b.w, s, a.w);
}

__device__ __forceinline__ ushort bfb(float f) {
  union { __hip_bfloat16 h; ushort u; } cv; cv.h = __float2bfloat16(f); return cv.u;
}
__device__ __forceinline__ uint pk2(float a, float b) {
  return ((uint)bfb(b) << 16) | (uint)bfb(a);
}
__device__ __forceinline__ uint pku(ushort a, ushort b) {
  return ((uint)b << 16) | (uint)a;
}
__device__ __forceinline__ bf16x8 ldfrag(const void* p) {
  union { uint4 u; bf16x8 v; } cv; cv.u = *reinterpret_cast<const uint4*>(p); return cv.v;
}
__device__ __forceinline__ bf16x8 mkfrag(uint a, uint b, uint c, uint d) {
  union { uint4 u; bf16x8 v; } cv; cv.u = make_uint4(a,b,c,d); return cv.v;
}
__device__ __forceinline__ float bflo(uint w) { return __uint_as_float(w << 16); }
__device__ __forceinline__ float bfhi(uint w) { return __uint_as_float(w & 0xffff0000u); }
__device__ __forceinline__ float bf2f(ushort u) { return __uint_as_float(((uint)u) << 16); }

struct SIdx { int r[8]; float v[6]; };
__device__ __forceinline__ SIdx load_idx(const Ptrs& P, unsigned s) {
  SIdx o;
  o.r[0] = P.br1[s];      o.r[1] = 15 + P.tp1[s];
  o.r[2] = 24 + P.br2[s]; o.r[3] = 39 + P.tp2[s];
  o.r[4] = 48 + P.sz1[s]; o.r[5] = 51 + P.en1[s];
  o.r[6] = 54 + P.sz2[s]; o.r[7] = 57 + P.en2[s];
  o.v[0] = P.ag1[s]*(1.0f/15.0f); o.v[1] = P.so1[s]; o.v[2] = P.wt1[s]*0.01f;
  o.v[3] = P.ag2[s]*(1.0f/15.0f); o.v[4] = P.so2[s]; o.v[5] = P.wt2[s]*0.01f;
  return o;
}

// tree-reassociated gather
__device__ __forceinline__ float4 gather4(const float* Tl, const float* contT,
                                          const int rb[8], const float v[6], int c) {
  float4 A = f4add(f4add(ld4(Tl+rb[0]+c), ld4(Tl+rb[1]+c)),
                   f4add(ld4(Tl+rb[2]+c), ld4(Tl+rb[3]+c)));
  float4 B = f4add(f4add(ld4(Tl+rb[4]+c), ld4(Tl+rb[5]+c)),
                   f4add(ld4(Tl+rb[6]+c), ld4(Tl+rb[7]+c)));
  A = f4fma(A, ld4(contT + 60*TSTR + c), v[0]);
  A = f4fma(A, ld4(contT + 61*TSTR + c), v[1]);
  A = f4fma(A, ld4(contT + 62*TSTR + c), v[2]);
  B = f4fma(B, ld4(contT + 63*TSTR + c), v[3]);
  B = f4fma(B, ld4(contT + 64*TSTR + c), v[4]);
  B = f4fma(B, ld4(contT + 65*TSTR + c), v[5]);
  return f4add(A, B);
}

__device__ __forceinline__ void load_rb(const Ptrs& P, unsigned s, int rb[8], float v[6]) {
  SIdx o = load_idx(P, s);
  #pragma unroll
  for (int i = 0; i < 8; ++i) rb[i] = o.r[i]*TSTR;
  #pragma unroll
  for (int i = 0; i < 6; ++i) v[i] = o.v[i];
}

__device__ __forceinline__ void stage_tab(const float* wsT, const float* params,
                                          float* Tl, bool bn1) {
  for (int i = threadIdx.x; i < NTABROWS*TSTR; i += blockDim.x) Tl[i] = wsT[i];
  if (bn1) {
    for (int i = threadIdx.x; i < 128; i += blockDim.x) {
      Tl[66*TSTR + i] = params[i];
      Tl[67*TSTR + i] = params[128 + i];
    }
  }
  __syncthreads();
}

__device__ __forceinline__ void x2_from_lds(const float* Tl, const int rb[8], const float v[6],
                                            const float* W2, const float* b2, float4 acc[16]) {
  #pragma unroll
  for (int j4 = 0; j4 < 16; ++j4) acc[j4] = ld4(b2 + j4*4);
  #pragma unroll 1
  for (int c4 = 0; c4 < 32; ++c4) {
    const int c = c4 * 4;
    float4 x = gather4(Tl, Tl, rb, v, c);
    const float4 sc = *reinterpret_cast<const float4*>(Tl + 66*TSTR + c);
    const float4 sh = *reinterpret_cast<const float4*>(Tl + 67*TSTR + c);
    float hv[4];
    hv[0] = fmaxf(fmaf(x.x, sc.x, sh.x), 0.0f);
    hv[1] = fmaxf(fmaf(x.y, sc.y, sh.y), 0.0f);
    hv[2] = fmaxf(fmaf(x.z, sc.z, sh.z), 0.0f);
    hv[3] = fmaxf(fmaf(x.w, sc.w, sh.w), 0.0f);
    #pragma unroll
    for (int r = 0; r < 4; ++r) {
      const float hr = hv[r];
      const float4* w = reinterpret_cast<const float4*>(W2 + (c + r)*64);
      #pragma unroll
      for (int j4 = 0; j4 < 16; ++j4) fma4s(acc[j4], w[j4], hr);
    }
  }
}

__device__ __forceinline__ void x3_from_acc2(const float4 acc2[16], const Ptrs& P,
                                             const float* sc2, const float* sh2,
                                             float4 acc3[8]) {
  #pragma unroll
  for (int j4 = 0; j4 < 8; ++j4) acc3[j4] = ld4(P.b3 + j4*4);
  #pragma unroll
  for (int k4 = 0; k4 < 16; ++k4) {
    const float4 a = acc2[k4];
    const float4 sc = ld4(sc2 + k4*4), sh = ld4(sh2 + k4*4);
    const float hr[4] = {
      fmaxf(fmaf(a.x, sc.x, sh.x), 0.0f),
      fmaxf(fmaf(a.y, sc.y, sh.y), 0.0f),
      fmaxf(fmaf(a.z, sc.z, sh.z), 0.0f),
      fmaxf(fmaf(a.w, sc.w, sh.w), 0.0f)};
    #pragma unroll
    for (int r = 0; r < 4; ++r) {
      const float4* w = reinterpret_cast<const float4*>(P.W3 + (k4*4 + r)*32);
      #pragma unroll
      for (int j4 = 0; j4 < 8; ++j4) fma4s(acc3[j4], w[j4], hr[r]);
    }
  }
}

__device__ __forceinline__ float bfly_tail32(float st[32], int lane) {
#define BSTEP(D) { const bool h = (lane & D) != 0; \
  _Pragma("unroll") \
  for (int i = 0; i < D; ++i) { \
    float mine = h ? st[i] : st[i+D]; \
    float oth  = __shfl_xor(mine, D, 64); \
    float keep = h ? st[i+D] : st[i]; \
    st[i] = keep + oth; } }
  BSTEP(16) BSTEP(8) BSTEP(4) BSTEP(2) BSTEP(1)
#undef BSTEP
  return st[0];
}

template<bool SQ>
__device__ __forceinline__ float bfly64_from(const float4 acc[16], int lane) {
  float st[32];
  const bool hi = (lane & 32) != 0;
  #pragma unroll
  for (int j4 = 0; j4 < 8; ++j4) {
#define DO1(comp, idx) { \
    float lo = acc[j4].comp, hc = acc[j4+8].comp; \
    if (SQ) { lo *= lo; hc *= hc; } \
    float mine = hi ? lo : hc; \
    float keep = hi ? hc : lo; \
    st[4*j4+idx] = keep + __shfl_xor(mine, 32, 64); }
    DO1(x,0) DO1(y,1) DO1(z,2) DO1(w,3)
#undef DO1
  }
  return bfly_tail32(st, lane);
}

template<bool SQ>
__device__ __forceinline__ float bfly32_from(const float4 acc3[8], int lane) {
  float st[32];
  const bool hi = (lane & 32) != 0;
  #pragma unroll
  for (int j4 = 0; j4 < 8; ++j4) {
#define DO1(comp, idx) { \
    float vv = acc3[j4].comp; \
    if (SQ) vv *= vv; \
    float mine = hi ? vv : 0.0f; \
    float keep = hi ? 0.0f : vv; \
    st[4*j4+idx] = keep + __shfl_xor(mine, 32, 64); }
    DO1(x,0) DO1(y,1) DO1(z,2) DO1(w,3)
#undef DO1
  }
  return bfly_tail32(st, lane);
}

// feature-slot -> table-row mapping (round-10 VERIFIED end-to-end).
// t = 8*kk+e, lane quadrant q. Returns row index or -1 (zero); const slot -> -1 (raw table).
__device__ __forceinline__ int frag_row(int t, int q) {
  if (t < 4)       { if (t == 3 && q == 3) return -1; const int b = 4*t + q; return (b <= 14) ? b : -1; }
  else if (t < 7)  { if (t == 6 && q >= 1) return 60 + (q-1); const int vv = 4*(t-4)+q; return (vv <= 8) ? 15 + vv : -1; }
  else if (t == 7) { return (q <= 2) ? 48 + q : -1; }
  else if (t < 12) { const int b = 4*(t-8)+q; return (b <= 14) ? 24 + b : -1; }
  else if (t < 15) { if (t == 14 && q >= 1) return 63 + (q-1); const int vv = 4*(t-12)+q; return (vv <= 8) ? 39 + vv : -1; }
  else if (t == 15){ return (q <= 2) ? 51 + q : -1; }
  else if (t == 16){ return (q <= 2) ? 54 + q : -1; }
  else if (t == 17){ return (q <= 2) ? 57 + q : -1; }
  return -1;
}

// ---------------- kernels ----------------

__global__ __launch_bounds__(256) void k_prep(Ptrs P) {
  const int t = threadIdx.x;
  float* T = P.ws;
  {
    float* st = (float*)((char*)P.ws + OFF_STATS);
    for (int i = t; i < 224*16; i += 256) st[i] = 0.0f;
  }
  if (t < 128) {
    const int c = t;
    for (int b = 0; b < 15; ++b) {
      float a1 = P.b1[c], a2 = 0.0f;
      #pragma unroll
      for (int e = 0; e < 8; ++e) {
        a1 = fmaf(P.bemb[b*8+e], P.W1[e*128 + c], a1);
        a2 = fmaf(P.bemb[b*8+e], P.W1[(25+e)*128 + c], a2);
      }
      T[b*TSTR + c] = a1; T[(24+b)*TSTR + c] = a2;
    }
    for (int tt = 0; tt < 9; ++tt) {
      float a1 = 0.0f, a2 = 0.0f;
      #pragma unroll
      for (int e = 0; e < 8; ++e) {
        a1 = fmaf(P.temb[tt*8+e], P.W1[(14+e)*128 + c], a1);
        a2 = fmaf(P.temb[tt*8+e], P.W1[(39+e)*128 + c], a2);
      }
      T[(15+tt)*TSTR + c] = a1; T[(39+tt)*TSTR + c] = a2;
    }
    #pragma unroll
    for (int i = 0; i < 3; ++i) {
      T[(48+i)*TSTR + c] = P.W1[(8+i)*128 + c];
      T[(51+i)*TSTR + c] = P.W1[(11+i)*128 + c];
      T[(54+i)*TSTR + c] = P.W1[(33+i)*128 + c];
      T[(57+i)*TSTR + c] = P.W1[(36+i)*128 + c];
    }
    const int cr[6] = {22,23,24,47,48,49};
    #pragma unroll
    for (int m = 0; m < 6; ++m) T[(60+m)*TSTR + c] = P.W1[cr[m]*128 + c];
  }
  __syncthreads();
  __hip_bfloat16* w2f = (__hip_bfloat16*)((char*)P.ws + OFF_W2F);
  for (int slot = t; slot < 1024; slot += 256) {
    const int fid = slot >> 6, l = slot & 63;
    const int mt = fid >> 2, kk = fid & 3, q = l >> 4, m = l & 15;
    #pragma unroll
    for (int e = 0; e < 8; ++e)
      w2f[slot*8 + e] = __float2bfloat16(P.W2[(kk*32 + 8*q + e)*64 + 16*mt + m]);
  }
  __hip_bfloat16* w3f = (__hip_bfloat16*)((char*)P.ws + OFF_W3F);
  for (int slot = t; slot < 256; slot += 256) {
    const int fid = slot >> 6, l = slot & 63;
    const int mt = fid >> 1, kk = fid & 1, q = l >> 4, m = l & 15;
    #pragma unroll
    for (int e = 0; e < 8; ++e)
      w3f[slot*8 + e] = __float2bfloat16(P.W3[(kk*32 + 8*q + e)*32 + 16*mt + m]);
  }
  // RAW T^T A-frags, hi/lo bf16 split. fid=(mt*3+kk)*2+hl; 48 frags.
  uint4* w1s = (uint4*)((char*)P.ws + OFF_W1S);
  for (int slot = t; slot < 3072; slot += 256) {
    const int fid = slot >> 6, l = slot & 63;
    const int hl = fid & 1, mk = fid >> 1;
    const int kk = mk % 3, mt = mk / 3;
    const int q = l >> 4, m = l & 15, ch = 16*mt + m;
    ushort out[8];
    #pragma unroll
    for (int e = 0; e < 8; ++e) {
      const int row = frag_row(8*kk + e, q);
      const float val = (row >= 0) ? T[row*TSTR + ch] : 0.0f;
      const ushort hib = bfb(val);
      out[e] = (hl == 0) ? hib : bfb(val - bf2f(hib));
    }
    w1s[slot] = make_uint4(pku(out[0],out[1]), pku(out[2],out[3]),
                           pku(out[4],out[5]), pku(out[6],out[7]));
  }
}

// BN1 stats via feature-MFMA (round-10-verified layout), single reusable D,
// sums/sqs accumulated per-lane, wave m16-reduce, LDS sred, global atomics.
__global__ __launch_bounds__(512) void k_stats1m(Ptrs P) {
  __shared__ __align__(16) char Wl[49152];
  __shared__ float sred[256];
  {
    const uint4* src = (const uint4*)((const char*)P.ws + OFF_W1S);
    uint4* dst = (uint4*)Wl;
    for (int i = threadIdx.x; i < 3072; i += 512) dst[i] = src[i];
  }
  if (threadIdx.x < 256) sred[threadIdx.x] = 0.f;
  __syncthreads();
  const int lane = threadIdx.x & 63;
  const int q = lane >> 4, m16 = lane & 15;
  f32x4 sums[8], sqs[8];
  #pragma unroll
  for (int mt = 0; mt < 8; ++mt) { sums[mt] = (f32x4){0,0,0,0}; sqs[mt] = (f32x4){0,0,0,0}; }
  const unsigned nw = (gridDim.x*512) >> 6;
  const unsigned NT = BATCH >> 4;
  const ushort ONE = 0x3F80;
  for (unsigned it = (blockIdx.x*512 + threadIdx.x) >> 6; it < NT; it += nw) {
    const unsigned s = it*16 + m16;
    const int c0 = P.br1[s], c1 = P.tp1[s], c2 = P.br2[s], c3 = P.tp2[s];
    const int c4i = P.sz1[s], c5 = P.en1[s], c6 = P.sz2[s], c7 = P.en2[s];
    const ushort vb0 = bfb(P.ag1[s]*(1.0f/15.0f)), vb1 = bfb(P.so1[s]);
    const ushort vb2 = bfb(P.wt1[s]*0.01f);
    const ushort vb3 = bfb(P.ag2[s]*(1.0f/15.0f)), vb4 = bfb(P.so2[s]);
    const ushort vb5 = bfb(P.wt2[s]*0.01f);
#define INDE(cv, tgt) ((ushort)(((cv) == (tgt)) ? ONE : 0))
    const ushort e0 = INDE(c0, q),     e1 = INDE(c0, 4+q);
    const ushort e2 = INDE(c0, 8+q);
    const ushort e3 = (q == 3) ? ONE : INDE(c0, 12+q);
    const ushort e4 = INDE(c1, q),     e5 = INDE(c1, 4+q);
    const ushort e6 = (q == 0) ? INDE(c1, 8)
                               : ((q == 1) ? vb0 : (q == 2) ? vb1 : vb2);
    const ushort e7 = INDE(c4i, q);
    const ushort f0 = INDE(c2, q),     f1 = INDE(c2, 4+q);
    const ushort f2 = INDE(c2, 8+q),   f3 = INDE(c2, 12+q);
    const ushort f4 = INDE(c3, q),     f5 = INDE(c3, 4+q);
    const ushort f6 = (q == 0) ? INDE(c3, 8)
                               : ((q == 1) ? vb3 : (q == 2) ? vb4 : vb5);
    const ushort f7 = INDE(c5, q);
    const ushort g0 = INDE(c6, q),     g1 = INDE(c7, q);
#undef INDE
    const bf16x8 B0 = mkfrag(pku(e0,e1), pku(e2,e3), pku(e4,e5), pku(e6,e7));
    const bf16x8 B1 = mkfrag(pku(f0,f1), pku(f2,f3), pku(f4,f5), pku(f6,f7));
    const bf16x8 B2 = mkfrag(pku(g0,g1), 0u, 0u, 0u);
    #pragma unroll
    for (int mt = 0; mt < 8; ++mt) {
      f32x4 D = (f32x4){0.f,0.f,0.f,0.f};
      #pragma unroll
      for (int kk = 0; kk < 3; ++kk) {
        const bf16x8 bf = (kk == 0) ? B0 : (kk == 1) ? B1 : B2;
        const bf16x8 ah = ldfrag(Wl + (size_t)(((mt*3+kk)*2+0)*64 + lane)*16);
        D = __builtin_amdgcn_mfma_f32_16x16x32_bf16(ah, bf, D, 0, 0, 0);
        const bf16x8 al = ldfrag(Wl + (size_t)(((mt*3+kk)*2+1)*64 + lane)*16);
        D = __builtin_amdgcn_mfma_f32_16x16x32_bf16(al, bf, D, 0, 0, 0);
      }
      #pragma unroll
      for (int r = 0; r < 4; ++r) {
        sums[mt][r] += D[r];
        sqs[mt][r]   = fmaf(D[r], D[r], sqs[mt][r]);
      }
    }
  }
  #pragma unroll
  for (int d = 1; d <= 8; d <<= 1) {
    #pragma unroll
    for (int mt = 0; mt < 8; ++mt) {
      #pragma unroll
      for (int r = 0; r < 4; ++r) {
        sums[mt][r] += __shfl_xor(sums[mt][r], d, 64);
        sqs[mt][r]  += __shfl_xor(sqs[mt][r],  d, 64);
      }
    }
  }
  if (m16 == 0) {
    #pragma unroll
    for (int mt = 0; mt < 8; ++mt) {
      #pragma unroll
      for (int r = 0; r < 4; ++r) {
        const int ch = 16*mt + 4*q + r;
        atomicAdd(&sred[ch], sums[mt][r]);
        atomicAdd(&sred[128+ch], sqs[mt][r]);
      }
    }
  }
  __syncthreads();
  if (threadIdx.x < 128) {
    float* stat = (float*)((char*)P.ws + OFF_STATS) + (size_t)threadIdx.x*16;
    atomicAdd(stat,     sred[threadIdx.x]);
    atomicAdd(stat + 8, sred[128+threadIdx.x]);
  }
}

// BN1 stats by direct encode (FALLBACK path only)
__global__ __launch_bounds__(512) void k_stats1(Ptrs P) {
  __shared__ __align__(16) float Tl[60*TSTR];
  __shared__ float sred[256];
  for (int i = threadIdx.x; i < 60*TSTR; i += 512) Tl[i] = P.ws[i];
  if (threadIdx.x < 256) sred[threadIdx.x] = 0.f;
  __syncthreads();
  const int lane = threadIdx.x & 63;
  const int q = lane >> 4, m16 = lane & 15;
  const float* contT = P.ws;
  const unsigned gw = (blockIdx.x*512 + threadIdx.x) >> 6;
  const unsigned nw = (gridDim.x*512) >> 6;
  const int kk = gw & 3;
  const int c = kk*32 + 8*q;
  const unsigned NT = BATCH >> 4;
  unsigned it = gw >> 2;
  const unsigned ts = nw >> 2;
  float4 sa = make_float4(0,0,0,0), sb = sa, qa = sa, qb = sa;
  bool active = it < NT;
  int rb[8]; float v[6];
  if (active) load_rb(P, it*16 + m16, rb, v);
  while (active) {
    const unsigned itn = it + ts;
    const bool more = itn < NT;
    int rbn[8]; float vn[6];
    if (more) load_rb(P, itn*16 + m16, rbn, vn);
    const float4 xa = gather4(Tl, contT, rb, v, c);
    const float4 xb = gather4(Tl, contT, rb, v, c + 4);
    add4(sa, xa); add4(sb, xb);
    qa.x = fmaf(xa.x, xa.x, qa.x); qa.y = fmaf(xa.y, xa.y, qa.y);
    qa.z = fmaf(xa.z, xa.z, qa.z); qa.w = fmaf(xa.w, xa.w, qa.w);
    qb.x = fmaf(xb.x, xb.x, qb.x); qb.y = fmaf(xb.y, xb.y, qb.y);
    qb.z = fmaf(xb.z, xb.z, qb.z); qb.w = fmaf(xb.w, xb.w, qb.w);
    if (!more) break;
    #pragma unroll
    for (int i = 0; i < 8; ++i) rb[i] = rbn[i];
    #pragma unroll
    for (int i = 0; i < 6; ++i) v[i] = vn[i];
    it = itn;
  }
  #pragma unroll
  for (int d = 1; d <= 8; d <<= 1) {
    sa.x += __shfl_xor(sa.x, d, 64); sa.y += __shfl_xor(sa.y, d, 64);
    sa.z += __shfl_xor(sa.z, d, 64); sa.w += __shfl_xor(sa.w, d, 64);
    sb.x += __shfl_xor(sb.x, d, 64); sb.y += __shfl_xor(sb.y, d, 64);
    sb.z += __shfl_xor(sb.z, d, 64); sb.w += __shfl_xor(sb.w, d, 64);
    qa.x += __shfl_xor(qa.x, d, 64); qa.y += __shfl_xor(qa.y, d, 64);
    qa.z += __shfl_xor(qa.z, d, 64); qa.w += __shfl_xor(qa.w, d, 64);
    qb.x += __shfl_xor(qb.x, d, 64); qb.y += __shfl_xor(qb.y, d, 64);
    qb.z += __shfl_xor(qb.z, d, 64); qb.w += __shfl_xor(qb.w, d, 64);
  }
  if (m16 == 0) {
    atomicAdd(&sred[c+0], sa.x); atomicAdd(&sred[c+1], sa.y);
    atomicAdd(&sred[c+2], sa.z); atomicAdd(&sred[c+3], sa.w);
    atomicAdd(&sred[c+4], sb.x); atomicAdd(&sred[c+5], sb.y);
    atomicAdd(&sred[c+6], sb.z); atomicAdd(&sred[c+7], sb.w);
    atomicAdd(&sred[128+c+0], qa.x); atomicAdd(&sred[128+c+1], qa.y);
    atomicAdd(&sred[128+c+2], qa.z); atomicAdd(&sred[128+c+3], qa.w);
    atomicAdd(&sred[128+c+4], qb.x); atomicAdd(&sred[128+c+5], qb.y);
    atomicAdd(&sred[128+c+6], qb.z); atomicAdd(&sred[128+c+7], qb.w);
  }
  __syncthreads();
  if (threadIdx.x < 128) {
    float* stat = (float*)((char*)P.ws + OFF_STATS) + (size_t)threadIdx.x*16;
    atomicAdd(stat,     sred[threadIdx.x]);
    atomicAdd(stat + 8, sred[128+threadIdx.x]);
  }
}

// fallback-path finalize
__global__ void k_finalize(Ptrs P, int nch, int entry0, int pofs,
                           const float* g, const float* be) {
  const int c = threadIdx.x;
  if (c >= nch) return;
  const float* stat = (const float*)((const char*)P.ws + OFF_STATS) + (size_t)(entry0 + c)*16;
  const float mean = stat[0] * INV_B;
  const float var  = stat[8] * INV_B - mean*mean;
  const float inv  = 1.0f / sqrtf(var + EPSBN);
  const float scale = g[c] * inv;
  float* params = (float*)((char*)P.ws + OFF_PARAMS);
  params[pofs + c]       = scale;
  params[pofs + nch + c] = be[c] - mean * scale;
}

// Layer2 MFMA, LEAN (round-9 proven): in-kernel BN1 finalize into LDS bn[].
__global__ __launch_bounds__(512) void k_l2m(Ptrs P) {
  __shared__ __align__(16) float Tl[60*TSTR];
  __shared__ __align__(16) float bn[256];   // sc1[0..127], sh1[128..255]
  for (int i = threadIdx.x; i < 60*TSTR; i += 512) Tl[i] = P.ws[i];
  if (threadIdx.x < 128) {
    const float* stat = (const float*)((const char*)P.ws + OFF_STATS) + (size_t)threadIdx.x*16;
    const float mean = stat[0] * INV_B;
    const float var  = stat[8] * INV_B - mean*mean;
    const float scale = P.g1[threadIdx.x] / sqrtf(var + EPSBN);
    bn[threadIdx.x]       = scale;
    bn[128 + threadIdx.x] = P.be1[threadIdx.x] - mean * scale;
  }
  __syncthreads();
  const float* contT = P.ws;
  const int lane = threadIdx.x & 63;
  const int q = lane >> 4, m16 = lane & 15;
  const char* w2fB = (const char*)P.ws + OFF_W2F;
  char* x2B = (char*)P.ws + OFF_X2;
  const unsigned nw = (gridDim.x*512) >> 6;
  const unsigned NT = BATCH >> 4;
  unsigned it = (blockIdx.x*512 + threadIdx.x) >> 6;
  if (it >= NT) return;
  SIdx cur = load_idx(P, it*16 + m16);
  while (true) {
    const unsigned itn = it + nw;
    const bool more = itn < NT;
    SIdx nxt;
    if (more) nxt = load_idx(P, itn*16 + m16);   // prefetch next tile's indices
    const unsigned s = it*16 + m16;
    int rb[8];
    #pragma unroll
    for (int i = 0; i < 8; ++i) rb[i] = cur.r[i]*TSTR;
    f32x4 D[4];
    #pragma unroll
    for (int mt = 0; mt < 4; ++mt) {
      const float4 b = ld4(P.b2 + 16*mt + 4*q);
      D[mt][0] = b.x; D[mt][1] = b.y; D[mt][2] = b.z; D[mt][3] = b.w;
    }
    #pragma unroll
    for (int kk = 0; kk < 4; ++kk) {
      const int c = kk*32 + 8*q;
      const float4 xa = gather4(Tl, contT, rb, cur.v, c);
      const float4 xb = gather4(Tl, contT, rb, cur.v, c + 4);
      const float4 sca = ld4(bn + c), sha = ld4(bn + 128 + c);
      const float4 scb = ld4(bn + c + 4), shb = ld4(bn + 128 + c + 4);
      const float h0 = fmaxf(fmaf(xa.x, sca.x, sha.x), 0.f);
      const float h1 = fmaxf(fmaf(xa.y, sca.y, sha.y), 0.f);
      const float h2 = fmaxf(fmaf(xa.z, sca.z, sha.z), 0.f);
      const float h3 = fmaxf(fmaf(xa.w, sca.w, sha.w), 0.f);
      const float h4 = fmaxf(fmaf(xb.x, scb.x, shb.x), 0.f);
      const float h5 = fmaxf(fmaf(xb.y, scb.y, shb.y), 0.f);
      const float h6 = fmaxf(fmaf(xb.z, scb.z, shb.z), 0.f);
      const float h7 = fmaxf(fmaf(xb.w, scb.w, shb.w), 0.f);
      const bf16x8 bf = mkfrag(pk2(h0,h1), pk2(h2,h3), pk2(h4,h5), pk2(h6,h7));
      #pragma unroll
      for (int mt = 0; mt < 4; ++mt) {
        const bf16x8 af = ldfrag(w2fB + (size_t)((mt*4+kk)*64 + lane)*16);
        D[mt] = __builtin_amdgcn_mfma_f32_16x16x32_bf16(af, bf, D[mt], 0, 0, 0);
      }
    }
    #pragma unroll
    for (int mt = 0; mt < 4; ++mt) {
      const uint lo = pk2(D[mt][0], D[mt][1]);
      const uint hi = pk2(D[mt][2], D[mt][3]);
      *reinterpret_cast<uint2*>(x2B + (size_t)s*128 + (16*mt + 4*q)*2) = make_uint2(lo, hi);
    }
    if (!more) break;
    cur = nxt; it = itn;
  }
}

// BN2 stats from stored bf16 x2 (round-9)
__global__ __launch_bounds__(256) void k_stats2(Ptrs P) {
  const uint* x2u = (const uint*)((const char*)P.ws + OFF_X2);
  const int pid = threadIdx.x & 31;
  const int lane = threadIdx.x & 63;
  const int w = threadIdx.x >> 6;
  float slo = 0.f, shi = 0.f, qlo = 0.f, qhi = 0.f;
  const unsigned r0 = blockIdx.x*8 + (threadIdx.x >> 5);
  const unsigned rs = gridDim.x*8;
  #pragma unroll 4
  for (unsigned r = r0; r < BATCH; r += rs) {
    const uint u = x2u[(size_t)r*32 + pid];
    const float lo = bflo(u), hi = bfhi(u);
    slo += lo; shi += hi;
    qlo = fmaf(lo, lo, qlo); qhi = fmaf(hi, hi, qhi);
  }
  slo += __shfl_xor(slo, 32, 64); shi += __shfl_xor(shi, 32, 64);
  qlo += __shfl_xor(qlo, 32, 64); qhi += __shfl_xor(qhi, 32, 64);
  __shared__ float red[512];
  if (lane < 32) {
    red[w*64 + 2*pid]       = slo; red[w*64 + 2*pid + 1]       = shi;
    red[256 + w*64 + 2*pid] = qlo; red[256 + w*64 + 2*pid + 1] = qhi;
  }
  __syncthreads();
  if (threadIdx.x < 64) {
    const int c = threadIdx.x;
    const float s  = red[c] + red[64+c] + red[128+c] + red[192+c];
    const float qq = red[256+c] + red[320+c] + red[384+c] + red[448+c];
    float* stat = (float*)((char*)P.ws + OFF_STATS) + (size_t)(128 + c)*16;
    atomicAdd(stat, s); atomicAdd(stat + 8, qq);
  }
}

// Layer3 MFMA (round-9): in-kernel BN2 finalize; x2 prefetch; optional dense x3
__global__ __launch_bounds__(256) void k_l3m(Ptrs P, int dense) {
  __shared__ __align__(16) float bn[128];
  if (threadIdx.x < 64) {
    const float* stat = (const float*)((const char*)P.ws + OFF_STATS) + (size_t)(128 + threadIdx.x)*16;
    const float mean = stat[0] * INV_B;
    const float var  = stat[8] * INV_B - mean*mean;
    const float scale = P.g2[threadIdx.x] / sqrtf(var + EPSBN);
    bn[threadIdx.x]      = scale;
    bn[64 + threadIdx.x] = P.be2[threadIdx.x] - mean * scale;
  }
  __syncthreads();
  const int lane = threadIdx.x & 63;
  const int q = lane >> 4, m16 = lane & 15;
  const char* w3fB = (const char*)P.ws + OFF_W3F;
  const char* xB = (const char*)P.ws + OFF_X2;
  char* x3B = dense ? ((char*)P.ws + OFF_X3D) : ((char*)P.ws + OFF_X2);
  const size_t x3str = dense ? 64 : 128;
  const unsigned nw = (gridDim.x*256) >> 6;
  const unsigned NT = BATCH >> 4;
  unsigned it = (blockIdx.x*256 + threadIdx.x) >> 6;
  if (it >= NT) return;
  unsigned s = it*16 + m16;
  uint4 u0 = *reinterpret_cast<const uint4*>(xB + (size_t)s*128 + q*16);
  uint4 u1 = *reinterpret_cast<const uint4*>(xB + (size_t)s*128 + 64 + q*16);
  while (true) {
    const unsigned itn = it + nw;
    const bool more = itn < NT;
    uint4 n0, n1;
    if (more) {
      const unsigned sn = itn*16 + m16;
      n0 = *reinterpret_cast<const uint4*>(xB + (size_t)sn*128 + q*16);
      n1 = *reinterpret_cast<const uint4*>(xB + (size_t)sn*128 + 64 + q*16);
    }
    f32x4 D[2];
    #pragma unroll
    for (int mt = 0; mt < 2; ++mt) {
      const float4 b = ld4(P.b3 + 16*mt + 4*q);
      D[mt][0] = b.x; D[mt][1] = b.y; D[mt][2] = b.z; D[mt][3] = b.w;
    }
    #pragma unroll
    for (int kk = 0; kk < 2; ++kk) {
      const uint4 u = (kk == 0) ? u0 : u1;
      const int c = kk*32 + 8*q;
      const float4 scA = ld4(bn + c), shA = ld4(bn + 64 + c);
      const float4 scB = ld4(bn + c + 4), shB = ld4(bn + 64 + c + 4);
      const uint w[4] = {u.x,u.y,u.z,u.w};
      const float h0 = fmaxf(fmaf(bflo(w[0]), scA.x, shA.x), 0.f);
      const float h1 = fmaxf(fmaf(bfhi(w[0]), scA.y, shA.y), 0.f);
      const float h2 = fmaxf(fmaf(bflo(w[1]), scA.z, shA.z), 0.f);
      const float h3 = fmaxf(fmaf(bfhi(w[1]), scA.w, shA.w), 0.f);
      const float h4 = fmaxf(fmaf(bflo(w[2]), scB.x, shB.x), 0.f);
      const float h5 = fmaxf(fmaf(bfhi(w[2]), scB.y, shB.y), 0.f);
      const float h6 = fmaxf(fmaf(bflo(w[3]), scB.z, shB.z), 0.f);
      const float h7 = fmaxf(fmaf(bfhi(w[3]), scB.w, shB.w), 0.f);
      const bf16x8 bf = mkfrag(pk2(h0,h1), pk2(h2,h3), pk2(h4,h5), pk2(h6,h7));
      #pragma unroll
      for (int mt = 0; mt < 2; ++mt) {
        const bf16x8 af = ldfrag(w3fB + (size_t)((mt*2+kk)*64 + lane)*16);
        D[mt] = __builtin_amdgcn_mfma_f32_16x16x32_bf16(af, bf, D[mt], 0, 0, 0);
      }
    }
    #pragma unroll
    for (int mt = 0; mt < 2; ++mt) {
      const uint lo = pk2(D[mt][0], D[mt][1]);
      const uint hi = pk2(D[mt][2], D[mt][3]);
      *reinterpret_cast<uint2*>(x3B + (size_t)s*x3str + (16*mt + 4*q)*2) = make_uint2(lo, hi);
    }
    if (!more) break;
    u0 = n0; u1 = n1; it = itn; s = it*16 + m16;
  }
}

// BN3 stats (round-9)
__global__ __launch_bounds__(256) void k_stats3(Ptrs P, int dense) {
  const uint* xu = dense ? (const uint*)((const char*)P.ws + OFF_X3D)
                         : (const uint*)((const char*)P.ws + OFF_X2);
  const unsigned rstr = dense ? 16 : 32;
  const int pid = threadIdx.x & 15;
  const int lane = threadIdx.x & 63;
  const int w = threadIdx.x >> 6;
  float slo = 0.f, shi = 0.f, qlo = 0.f, qhi = 0.f;
  const unsigned r0 = blockIdx.x*16 + (threadIdx.x >> 4);
  const unsigned rs = gridDim.x*16;
  #pragma unroll 4
  for (unsigned r = r0; r < BATCH; r += rs) {
    const uint u = xu[(size_t)r*rstr + pid];
    const float lo = bflo(u), hi = bfhi(u);
    slo += lo; shi += hi;
    qlo = fmaf(lo, lo, qlo); qhi = fmaf(hi, hi, qhi);
  }
  #pragma unroll
  for (int d = 16; d <= 32; d <<= 1) {
    slo += __shfl_xor(slo, d, 64); shi += __shfl_xor(shi, d, 64);
    qlo += __shfl_xor(qlo, d, 64); qhi += __shfl_xor(qhi, d, 64);
  }
  __shared__ float red[256];
  if (lane < 16) {
    red[w*32 + 2*pid]       = slo; red[w*32 + 2*pid + 1]       = shi;
    red[128 + w*32 + 2*pid] = qlo; red[128 + w*32 + 2*pid + 1] = qhi;
  }
  __syncthreads();
  if (threadIdx.x < 32) {
    const int c = threadIdx.x;
    const float s  = red[c] + red[32+c] + red[64+c] + red[96+c];
    const float qq = red[128+c] + red[160+c] + red[192+c] + red[224+c];
    float* stat = (float*)((char*)P.ws + OFF_STATS) + (size_t)(192 + c)*16;
    atomicAdd(stat, s); atomicAdd(stat + 8, qq);
  }
}

// Layer4 (round-9)
__global__ __launch_bounds__(256) void k_l4n(Ptrs P, int dense) {
  __shared__ float bn[64];
  if (threadIdx.x < 32) {
    const float* stat = (const float*)((const char*)P.ws + OFF_STATS) + (size_t)(192 + threadIdx.x)*16;
    const float mean = stat[0] * INV_B;
    const float var  = stat[8] * INV_B - mean*mean;
    const float scale = P.g3[threadIdx.x] / sqrtf(var + EPSBN);
    bn[threadIdx.x]      = scale;
    bn[32 + threadIdx.x] = P.be3[threadIdx.x] - mean * scale;
  }
  __syncthreads();
  const float* sc3 = bn, *sh3 = bn + 32;
  const char* xB = dense ? ((const char*)P.ws + OFF_X3D) : ((const char*)P.ws + OFF_X2);
  const size_t xstr = dense ? 64 : 128;
  const unsigned stride = gridDim.x * 256;
  for (unsigned s = blockIdx.x*256 + threadIdx.x; s < BATCH; s += stride) {
    float z = P.b4[0];
    #pragma unroll
    for (int c16 = 0; c16 < 4; ++c16) {
      const uint4 u = *reinterpret_cast<const uint4*>(xB + (size_t)s*xstr + c16*16);
      const uint w[4] = {u.x,u.y,u.z,u.w};
      #pragma unroll
      for (int j = 0; j < 4; ++j) {
        const int ch = c16*8 + 2*j;
        const float hlo = fmaxf(fmaf(bflo(w[j]), sc3[ch],   sh3[ch]),   0.f);
        const float hhi = fmaxf(fmaf(bfhi(w[j]), sc3[ch+1], sh3[ch+1]), 0.f);
        z = fmaf(hlo, P.W4[ch], z);
        z = fmaf(hhi, P.W4[ch+1], z);
      }
    }
    P.out[s] = 1.0f / (1.0f + __expf(-z));
  }
}

// -------- fallback (small ws): recompute path (round-9) --------
__global__ __launch_bounds__(256) void k_l2r(Ptrs P) {
  __shared__ __align__(16) float Tl[68*TSTR];
  __shared__ float red[512];
  const float* params = (const float*)((const char*)P.ws + OFF_PARAMS);
  stage_tab(P.ws, params, Tl, true);
  const int lane = threadIdx.x & 63;
  float4 sums[16], sqs[16];
  #pragma unroll
  for (int j4 = 0; j4 < 16; ++j4) {
    sums[j4] = make_float4(0.f,0.f,0.f,0.f);
    sqs[j4]  = make_float4(0.f,0.f,0.f,0.f);
  }
  const unsigned stride = gridDim.x * 256;
  for (unsigned s = blockIdx.x*256 + threadIdx.x; s < BATCH; s += stride) {
    int rb[8]; float v[6];
    load_rb(P, s, rb, v);
    float4 acc[16];
    x2_from_lds(Tl, rb, v, P.W2, P.b2, acc);
    #pragma unroll
    for (int j4 = 0; j4 < 16; ++j4) {
      add4(sums[j4], acc[j4]);
      sqs[j4].x = fmaf(acc[j4].x, acc[j4].x, sqs[j4].x);
      sqs[j4].y = fmaf(acc[j4].y, acc[j4].y, sqs[j4].y);
      sqs[j4].z = fmaf(acc[j4].z, acc[j4].z, sqs[j4].z);
      sqs[j4].w = fmaf(acc[j4].w, acc[j4].w, sqs[j4].w);
    }
  }
  const float psum = bfly64_from<false>(sums, lane);
  const float psq  = bfly64_from<false>(sqs,  lane);
  red[threadIdx.x] = psum; red[256 + threadIdx.x] = psq;
  __syncthreads();
  const int t = threadIdx.x;
  if (t < 64) {
    const float s0 = red[t] + red[t+64] + red[t+128] + red[t+192];
    const float q0 = red[256+t] + red[256+t+64] + red[256+t+128] + red[256+t+192];
    float* stat = (float*)((char*)P.ws + OFF_STATS) + (size_t)(128 + t)*16;
    atomicAdd(stat, s0); atomicAdd(stat + 8, q0);
  }
}

__global__ __launch_bounds__(256) void k_l3_rec(Ptrs P) {
  __shared__ __align__(16) float Tl[68*TSTR];
  __shared__ float red[512];
  const float* params = (const float*)((const char*)P.ws + OFF_PARAMS);
  stage_tab(P.ws, params, Tl, true);
  const float* sc2 = params + 256, *sh2 = params + 320;
  const int lane = threadIdx.x & 63;
  float4 sums3[8], sqs3[8];
  #pragma unroll
  for (int j4 = 0; j4 < 8; ++j4) {
    sums3[j4] = make_float4(0.f,0.f,0.f,0.f);
    sqs3[j4]  = make_float4(0.f,0.f,0.f,0.f);
  }
  const unsigned stride = gridDim.x * 256;
  for (unsigned s = blockIdx.x*256 + threadIdx.x; s < BATCH; s += stride) {
    int rb[8]; float v[6];
    load_rb(P, s, rb, v);
    float4 acc2[16];
    x2_from_lds(Tl, rb, v, P.W2, P.b2, acc2);
    float4 acc3[8];
    x3_from_acc2(acc2, P, sc2, sh2, acc3);
    #pragma unroll
    for (int j4 = 0; j4 < 8; ++j4) {
      add4(sums3[j4], acc3[j4]);
      sqs3[j4].x = fmaf(acc3[j4].x, acc3[j4].x, sqs3[j4].x);
      sqs3[j4].y = fmaf(acc3[j4].y, acc3[j4].y, sqs3[j4].y);
      sqs3[j4].z = fmaf(acc3[j4].z, acc3[j4].z, sqs3[j4].z);
      sqs3[j4].w = fmaf(acc3[j4].w, acc3[j4].w, sqs3[j4].w);
    }
  }
  const float psum = bfly32_from<false>(sums3, lane);
  const float psq  = bfly32_from<false>(sqs3,  lane);
  red[threadIdx.x] = psum; red[256 + threadIdx.x] = psq;
  __syncthreads();
  const int t = threadIdx.x;
  if (t < 32) {
    const float s0 = red[t] + red[t+64] + red[t+128] + red[t+192];
    const float q0 = red[256+t] + red[256+t+64] + red[256+t+128] + red[256+t+192];
    float* stat = (float*)((char*)P.ws + OFF_STATS) + (size_t)(192 + t)*16;
    atomicAdd(stat, s0); atomicAdd(stat + 8, q0);
  }
}

__global__ __launch_bounds__(256) void k_l4_rec(Ptrs P) {
  __shared__ __align__(16) float Tl[68*TSTR];
  const float* params = (const float*)((const char*)P.ws + OFF_PARAMS);
  stage_tab(P.ws, params, Tl, true);
  const float* sc2 = params + 256, *sh2 = params + 320;
  const float* sc3 = params + 384, *sh3 = params + 416;
  const unsigned stride = gridDim.x * 256;
  for (unsigned s = blockIdx.x*256 + threadIdx.x; s < BATCH; s += stride) {
    int rb[8]; float v[6];
    load_rb(P, s, rb, v);
    float4 acc2[16];
    x2_from_lds(Tl, rb, v, P.W2, P.b2, acc2);
    float4 acc3[8];
    x3_from_acc2(acc2, P, sc2, sh2, acc3);
    float z = P.b4[0];
    #pragma unroll
    for (int k4 = 0; k4 < 8; ++k4) {
      const float4 a = acc3[k4];
      const float4 sc = ld4(sc3 + k4*4), sh = ld4(sh3 + k4*4);
      z = fmaf(fmaxf(fmaf(a.x, sc.x, sh.x), 0.0f), P.W4[k4*4+0], z);
      z = fmaf(fmaxf(fmaf(a.y, sc.y, sh.y), 0.0f), P.W4[k4*4+1], z);
      z = fmaf(fmaxf(fmaf(a.z, sc.z, sh.z), 0.0f), P.W4[k4*4+2], z);
      z = fmaf(fmaxf(fmaf(a.w, sc.w, sh.w), 0.0f), P.W4[k4*4+3], z);
    }
    P.out[s] = 1.0f / (1.0f + __expf(-z));
  }
}

// ---------------- host ----------------

extern "C" void kernel_launch(void* const* d_in, const int* in_sizes, int n_in,
                              void* d_out, int out_size, void* d_ws, size_t ws_size,
                              hipStream_t stream) {
  Ptrs P;
  P.br1 = (const int*)d_in[0];  P.sz1 = (const int*)d_in[1];
  P.en1 = (const int*)d_in[2];  P.tp1 = (const int*)d_in[3];
  P.ag1 = (const float*)d_in[4]; P.so1 = (const float*)d_in[5]; P.wt1 = (const float*)d_in[6];
  P.br2 = (const int*)d_in[7];  P.sz2 = (const int*)d_in[8];
  P.en2 = (const int*)d_in[9];  P.tp2 = (const int*)d_in[10];
  P.ag2 = (const float*)d_in[11]; P.so2 = (const float*)d_in[12]; P.wt2 = (const float*)d_in[13];
  P.bemb = (const float*)d_in[14]; P.temb = (const float*)d_in[15];
  P.W1 = (const float*)d_in[16]; P.b1 = (const float*)d_in[17];
  P.g1 = (const float*)d_in[18]; P.be1 = (const float*)d_in[19];
  P.W2 = (const float*)d_in[20]; P.b2 = (const float*)d_in[21];
  P.g2 = (const float*)d_in[22]; P.be2 = (const float*)d_in[23];
  P.W3 = (const float*)d_in[24]; P.b3 = (const float*)d_in[25];
  P.g3 = (const float*)d_in[26]; P.be3 = (const float*)d_in[27];
  P.W4 = (const float*)d_in[28]; P.b4 = (const float*)d_in[29];
  P.ws = (float*)d_ws; P.out = (float*)d_out;

  const bool t1 = ws_size >= T1_NEED;
  const int dense = (ws_size >= T2_NEED) ? 1 : 0;

  hipLaunchKernelGGL(k_prep, dim3(1), dim3(256), 0, stream, P);
  if (t1) {
    hipLaunchKernelGGL(k_stats1m, dim3(1024), dim3(512), 0, stream, P);
    hipLaunchKernelGGL(k_l2m, dim3(1024), dim3(512), 0, stream, P);
    hipLaunchKernelGGL(k_stats2, dim3(1024), dim3(256), 0, stream, P);
    hipLaunchKernelGGL(k_l3m, dim3(2048), dim3(256), 0, stream, P, dense);
    hipLaunchKernelGGL(k_stats3, dim3(1024), dim3(256), 0, stream, P, dense);
    hipLaunchKernelGGL(k_l4n, dim3(2048), dim3(256), 0, stream, P, dense);
  } else {
    hipLaunchKernelGGL(k_stats1, dim3(1024), dim3(512), 0, stream, P);
    hipLaunchKernelGGL(k_finalize, dim3(1), dim3(128), 0, stream, P, 128, 0, 0, P.g1, P.be1);
    hipLaunchKernelGGL(k_l2r, dim3(1024), dim3(256), 0, stream, P);
    hipLaunchKernelGGL(k_finalize, dim3(1), dim3(64), 0, stream, P, 64, 128, 256, P.g2, P.be2);
    hipLaunchKernelGGL(k_l3_rec, dim3(1024), dim3(256), 0, stream, P);
    hipLaunchKernelGGL(k_finalize, dim3(1), dim3(32), 0, stream, P, 32, 192, 384, P.g3, P.be3);
    hipLaunchKernelGGL(k_l4_rec, dim3(2048), dim3(256), 0, stream, P);
  }
}

// Round 15
// 550.996 us; speedup vs baseline: 2.0803x; 1.2060x over previous
//
#include <hip/hip_runtime.h>
#include <hip/hip_bf16.h>

#define BATCH (1u<<20)
static constexpr float EPSBN = 1e-5f;
static constexpr float INV_B = 1.0f / (float)BATCH;

typedef unsigned int   uint;
typedef unsigned short ushort;

// f32 master table at ws+0, stride 132 floats, rows 0-65:
// 0-14 breed1(+b1) | 15-23 temp1 | 24-38 breed2 | 39-47 temp2
// 48-50 sz1 | 51-53 en1 | 54-56 sz2 | 57-59 en2 | 60-65 continuous
#define TSTR 132
#define NTABROWS 66
#define OFF_W2F    55296ULL            // W2^T A-frags bf16: 16*64*16B
#define OFF_W3F    71680ULL            // W3^T A-frags bf16: 4*64*16B
#define OFF_STATS  75776ULL            // 224 entries * 64B (sum @+0, sumsq @+32B)
#define OFF_PARAMS 90112ULL            // 448 f32 (fallback path only)
#define OFF_W1S    94208ULL            // RAW T^T A-frags hi/lo: 48 frag * 1KB = 48KB
#define OFF_X2     147456ULL           // bf16 [B][64] 128B rows; x3 aliased into first 64B
#define OFF_X3D    (147456ULL + 134217728ULL)   // dense bf16 [B][32] (tier 2)
#define T1_NEED    (147456ULL + 134217728ULL)
#define T2_NEED    (147456ULL + 134217728ULL + 67108864ULL)

struct Ptrs {
  const int *br1,*sz1,*en1,*tp1; const float *ag1,*so1,*wt1;
  const int *br2,*sz2,*en2,*tp2; const float *ag2,*so2,*wt2;
  const float *bemb,*temb;
  const float *W1,*b1,*g1,*be1;
  const float *W2,*b2,*g2,*be2;
  const float *W3,*b3,*g3,*be3;
  const float *W4,*b4;
  float* ws; float* out;
};

typedef __attribute__((ext_vector_type(8))) short bf16x8;
typedef __attribute__((ext_vector_type(4))) float f32x4;

__device__ __forceinline__ float4 ld4(const float* p) {
  return *reinterpret_cast<const float4*>(p);
}
__device__ __forceinline__ float4 f4add(float4 a, float4 b) {
  return make_float4(a.x+b.x, a.y+b.y, a.z+b.z, a.w+b.w);
}
__device__ __forceinline__ float4 f4fma(float4 a, float4 w, float s) {
  return make_float4(fmaf(w.x,s,a.x), fmaf(w.y,s,a.y), fmaf(w.z,s,a.z), fmaf(w.w,s,a.w));
}
__device__ __forceinline__ void add4(float4& a, const float4 b) {
  a.x += b.x; a.y += b.y; a.z += b.z; a.w += b.w;
}
__device__ __forceinline__ void fma4s(float4& a, const float4 b, float s) {
  a.x = fmaf(b.x, s, a.x); a.y = fmaf(b.y, s, a.y);
  a.z = fmaf(b.z, s, a.z); a.w = fmaf(b.w, s, a.w);
}

__device__ __forceinline__ ushort bfb(float f) {
  union { __hip_bfloat16 h; ushort u; } cv; cv.h = __float2bfloat16(f); return cv.u;
}
__device__ __forceinline__ uint pk2(float a, float b) {
  return ((uint)bfb(b) << 16) | (uint)bfb(a);
}
__device__ __forceinline__ uint pku(ushort a, ushort b) {
  return ((uint)b << 16) | (uint)a;
}
__device__ __forceinline__ bf16x8 ldfrag(const void* p) {
  union { uint4 u; bf16x8 v; } cv; cv.u = *reinterpret_cast<const uint4*>(p); return cv.v;
}
__device__ __forceinline__ bf16x8 mkfrag(uint a, uint b, uint c, uint d) {
  union { uint4 u; bf16x8 v; } cv; cv.u = make_uint4(a,b,c,d); return cv.v;
}
__device__ __forceinline__ float bflo(uint w) { return __uint_as_float(w << 16); }
__device__ __forceinline__ float bfhi(uint w) { return __uint_as_float(w & 0xffff0000u); }
__device__ __forceinline__ float bf2f(ushort u) { return __uint_as_float(((uint)u) << 16); }

struct SIdx { int r[8]; float v[6]; };
__device__ __forceinline__ SIdx load_idx(const Ptrs& P, unsigned s) {
  SIdx o;
  o.r[0] = P.br1[s];      o.r[1] = 15 + P.tp1[s];
  o.r[2] = 24 + P.br2[s]; o.r[3] = 39 + P.tp2[s];
  o.r[4] = 48 + P.sz1[s]; o.r[5] = 51 + P.en1[s];
  o.r[6] = 54 + P.sz2[s]; o.r[7] = 57 + P.en2[s];
  o.v[0] = P.ag1[s]*(1.0f/15.0f); o.v[1] = P.so1[s]; o.v[2] = P.wt1[s]*0.01f;
  o.v[3] = P.ag2[s]*(1.0f/15.0f); o.v[4] = P.so2[s]; o.v[5] = P.wt2[s]*0.01f;
  return o;
}

// tree-reassociated gather
__device__ __forceinline__ float4 gather4(const float* Tl, const float* contT,
                                          const int rb[8], const float v[6], int c) {
  float4 A = f4add(f4add(ld4(Tl+rb[0]+c), ld4(Tl+rb[1]+c)),
                   f4add(ld4(Tl+rb[2]+c), ld4(Tl+rb[3]+c)));
  float4 B = f4add(f4add(ld4(Tl+rb[4]+c), ld4(Tl+rb[5]+c)),
                   f4add(ld4(Tl+rb[6]+c), ld4(Tl+rb[7]+c)));
  A = f4fma(A, ld4(contT + 60*TSTR + c), v[0]);
  A = f4fma(A, ld4(contT + 61*TSTR + c), v[1]);
  A = f4fma(A, ld4(contT + 62*TSTR + c), v[2]);
  B = f4fma(B, ld4(contT + 63*TSTR + c), v[3]);
  B = f4fma(B, ld4(contT + 64*TSTR + c), v[4]);
  B = f4fma(B, ld4(contT + 65*TSTR + c), v[5]);
  return f4add(A, B);
}

__device__ __forceinline__ void load_rb(const Ptrs& P, unsigned s, int rb[8], float v[6]) {
  SIdx o = load_idx(P, s);
  #pragma unroll
  for (int i = 0; i < 8; ++i) rb[i] = o.r[i]*TSTR;
  #pragma unroll
  for (int i = 0; i < 6; ++i) v[i] = o.v[i];
}

__device__ __forceinline__ void stage_tab(const float* wsT, const float* params,
                                          float* Tl, bool bn1) {
  for (int i = threadIdx.x; i < NTABROWS*TSTR; i += blockDim.x) Tl[i] = wsT[i];
  if (bn1) {
    for (int i = threadIdx.x; i < 128; i += blockDim.x) {
      Tl[66*TSTR + i] = params[i];
      Tl[67*TSTR + i] = params[128 + i];
    }
  }
  __syncthreads();
}

__device__ __forceinline__ void x2_from_lds(const float* Tl, const int rb[8], const float v[6],
                                            const float* W2, const float* b2, float4 acc[16]) {
  #pragma unroll
  for (int j4 = 0; j4 < 16; ++j4) acc[j4] = ld4(b2 + j4*4);
  #pragma unroll 1
  for (int c4 = 0; c4 < 32; ++c4) {
    const int c = c4 * 4;
    float4 x = gather4(Tl, Tl, rb, v, c);
    const float4 sc = *reinterpret_cast<const float4*>(Tl + 66*TSTR + c);
    const float4 sh = *reinterpret_cast<const float4*>(Tl + 67*TSTR + c);
    float hv[4];
    hv[0] = fmaxf(fmaf(x.x, sc.x, sh.x), 0.0f);
    hv[1] = fmaxf(fmaf(x.y, sc.y, sh.y), 0.0f);
    hv[2] = fmaxf(fmaf(x.z, sc.z, sh.z), 0.0f);
    hv[3] = fmaxf(fmaf(x.w, sc.w, sh.w), 0.0f);
    #pragma unroll
    for (int r = 0; r < 4; ++r) {
      const float hr = hv[r];
      const float4* w = reinterpret_cast<const float4*>(W2 + (c + r)*64);
      #pragma unroll
      for (int j4 = 0; j4 < 16; ++j4) fma4s(acc[j4], w[j4], hr);
    }
  }
}

__device__ __forceinline__ void x3_from_acc2(const float4 acc2[16], const Ptrs& P,
                                             const float* sc2, const float* sh2,
                                             float4 acc3[8]) {
  #pragma unroll
  for (int j4 = 0; j4 < 8; ++j4) acc3[j4] = ld4(P.b3 + j4*4);
  #pragma unroll
  for (int k4 = 0; k4 < 16; ++k4) {
    const float4 a = acc2[k4];
    const float4 sc = ld4(sc2 + k4*4), sh = ld4(sh2 + k4*4);
    const float hr[4] = {
      fmaxf(fmaf(a.x, sc.x, sh.x), 0.0f),
      fmaxf(fmaf(a.y, sc.y, sh.y), 0.0f),
      fmaxf(fmaf(a.z, sc.z, sh.z), 0.0f),
      fmaxf(fmaf(a.w, sc.w, sh.w), 0.0f)};
    #pragma unroll
    for (int r = 0; r < 4; ++r) {
      const float4* w = reinterpret_cast<const float4*>(P.W3 + (k4*4 + r)*32);
      #pragma unroll
      for (int j4 = 0; j4 < 8; ++j4) fma4s(acc3[j4], w[j4], hr[r]);
    }
  }
}

__device__ __forceinline__ float bfly_tail32(float st[32], int lane) {
#define BSTEP(D) { const bool h = (lane & D) != 0; \
  _Pragma("unroll") \
  for (int i = 0; i < D; ++i) { \
    float mine = h ? st[i] : st[i+D]; \
    float oth  = __shfl_xor(mine, D, 64); \
    float keep = h ? st[i+D] : st[i]; \
    st[i] = keep + oth; } }
  BSTEP(16) BSTEP(8) BSTEP(4) BSTEP(2) BSTEP(1)
#undef BSTEP
  return st[0];
}

template<bool SQ>
__device__ __forceinline__ float bfly64_from(const float4 acc[16], int lane) {
  float st[32];
  const bool hi = (lane & 32) != 0;
  #pragma unroll
  for (int j4 = 0; j4 < 8; ++j4) {
#define DO1(comp, idx) { \
    float lo = acc[j4].comp, hc = acc[j4+8].comp; \
    if (SQ) { lo *= lo; hc *= hc; } \
    float mine = hi ? lo : hc; \
    float keep = hi ? hc : lo; \
    st[4*j4+idx] = keep + __shfl_xor(mine, 32, 64); }
    DO1(x,0) DO1(y,1) DO1(z,2) DO1(w,3)
#undef DO1
  }
  return bfly_tail32(st, lane);
}

template<bool SQ>
__device__ __forceinline__ float bfly32_from(const float4 acc3[8], int lane) {
  float st[32];
  const bool hi = (lane & 32) != 0;
  #pragma unroll
  for (int j4 = 0; j4 < 8; ++j4) {
#define DO1(comp, idx) { \
    float vv = acc3[j4].comp; \
    if (SQ) vv *= vv; \
    float mine = hi ? vv : 0.0f; \
    float keep = hi ? 0.0f : vv; \
    st[4*j4+idx] = keep + __shfl_xor(mine, 32, 64); }
    DO1(x,0) DO1(y,1) DO1(z,2) DO1(w,3)
#undef DO1
  }
  return bfly_tail32(st, lane);
}

// feature-slot -> table-row mapping (round-10 VERIFIED end-to-end).
__device__ __forceinline__ int frag_row(int t, int q) {
  if (t < 4)       { if (t == 3 && q == 3) return -1; const int b = 4*t + q; return (b <= 14) ? b : -1; }
  else if (t < 7)  { if (t == 6 && q >= 1) return 60 + (q-1); const int vv = 4*(t-4)+q; return (vv <= 8) ? 15 + vv : -1; }
  else if (t == 7) { return (q <= 2) ? 48 + q : -1; }
  else if (t < 12) { const int b = 4*(t-8)+q; return (b <= 14) ? 24 + b : -1; }
  else if (t < 15) { if (t == 14 && q >= 1) return 63 + (q-1); const int vv = 4*(t-12)+q; return (vv <= 8) ? 39 + vv : -1; }
  else if (t == 15){ return (q <= 2) ? 51 + q : -1; }
  else if (t == 16){ return (q <= 2) ? 54 + q : -1; }
  else if (t == 17){ return (q <= 2) ? 57 + q : -1; }
  return -1;
}

// ---------------- kernels ----------------

__global__ __launch_bounds__(256) void k_prep(Ptrs P) {
  const int t = threadIdx.x;
  float* T = P.ws;
  {
    float* st = (float*)((char*)P.ws + OFF_STATS);
    for (int i = t; i < 224*16; i += 256) st[i] = 0.0f;
  }
  if (t < 128) {
    const int c = t;
    for (int b = 0; b < 15; ++b) {
      float a1 = P.b1[c], a2 = 0.0f;
      #pragma unroll
      for (int e = 0; e < 8; ++e) {
        a1 = fmaf(P.bemb[b*8+e], P.W1[e*128 + c], a1);
        a2 = fmaf(P.bemb[b*8+e], P.W1[(25+e)*128 + c], a2);
      }
      T[b*TSTR + c] = a1; T[(24+b)*TSTR + c] = a2;
    }
    for (int tt = 0; tt < 9; ++tt) {
      float a1 = 0.0f, a2 = 0.0f;
      #pragma unroll
      for (int e = 0; e < 8; ++e) {
        a1 = fmaf(P.temb[tt*8+e], P.W1[(14+e)*128 + c], a1);
        a2 = fmaf(P.temb[tt*8+e], P.W1[(39+e)*128 + c], a2);
      }
      T[(15+tt)*TSTR + c] = a1; T[(39+tt)*TSTR + c] = a2;
    }
    #pragma unroll
    for (int i = 0; i < 3; ++i) {
      T[(48+i)*TSTR + c] = P.W1[(8+i)*128 + c];
      T[(51+i)*TSTR + c] = P.W1[(11+i)*128 + c];
      T[(54+i)*TSTR + c] = P.W1[(33+i)*128 + c];
      T[(57+i)*TSTR + c] = P.W1[(36+i)*128 + c];
    }
    const int cr[6] = {22,23,24,47,48,49};
    #pragma unroll
    for (int m = 0; m < 6; ++m) T[(60+m)*TSTR + c] = P.W1[cr[m]*128 + c];
  }
  __syncthreads();
  __hip_bfloat16* w2f = (__hip_bfloat16*)((char*)P.ws + OFF_W2F);
  for (int slot = t; slot < 1024; slot += 256) {
    const int fid = slot >> 6, l = slot & 63;
    const int mt = fid >> 2, kk = fid & 3, q = l >> 4, m = l & 15;
    #pragma unroll
    for (int e = 0; e < 8; ++e)
      w2f[slot*8 + e] = __float2bfloat16(P.W2[(kk*32 + 8*q + e)*64 + 16*mt + m]);
  }
  __hip_bfloat16* w3f = (__hip_bfloat16*)((char*)P.ws + OFF_W3F);
  for (int slot = t; slot < 256; slot += 256) {
    const int fid = slot >> 6, l = slot & 63;
    const int mt = fid >> 1, kk = fid & 1, q = l >> 4, m = l & 15;
    #pragma unroll
    for (int e = 0; e < 8; ++e)
      w3f[slot*8 + e] = __float2bfloat16(P.W3[(kk*32 + 8*q + e)*32 + 16*mt + m]);
  }
  // RAW T^T A-frags, hi/lo bf16 split. fid=(mt*3+kk)*2+hl; 48 frags.
  uint4* w1s = (uint4*)((char*)P.ws + OFF_W1S);
  for (int slot = t; slot < 3072; slot += 256) {
    const int fid = slot >> 6, l = slot & 63;
    const int hl = fid & 1, mk = fid >> 1;
    const int kk = mk % 3, mt = mk / 3;
    const int q = l >> 4, m = l & 15, ch = 16*mt + m;
    ushort out[8];
    #pragma unroll
    for (int e = 0; e < 8; ++e) {
      const int row = frag_row(8*kk + e, q);
      const float val = (row >= 0) ? T[row*TSTR + ch] : 0.0f;
      const ushort hib = bfb(val);
      out[e] = (hl == 0) ? hib : bfb(val - bf2f(hib));
    }
    w1s[slot] = make_uint4(pku(out[0],out[1]), pku(out[2],out[3]),
                           pku(out[4],out[5]), pku(out[6],out[7]));
  }
}

// BN1 stats via feature-MFMA; WAVE mt-HALF SPECIALIZATION (32 acc regs, not 64).
__global__ __launch_bounds__(512) void k_stats1m(Ptrs P) {
  __shared__ __align__(16) char Wl[49152];
  __shared__ float sred[256];
  {
    const uint4* src = (const uint4*)((const char*)P.ws + OFF_W1S);
    uint4* dst = (uint4*)Wl;
    for (int i = threadIdx.x; i < 3072; i += 512) dst[i] = src[i];
  }
  if (threadIdx.x < 256) sred[threadIdx.x] = 0.f;
  __syncthreads();
  const int lane = threadIdx.x & 63;
  const int q = lane >> 4, m16 = lane & 15;
  const unsigned gw = (blockIdx.x*512 + threadIdx.x) >> 6;
  const unsigned nw = (gridDim.x*512) >> 6;
  const int mt0 = (gw & 1) * 4;      // wave handles mt0..mt0+3 (32 acc VGPRs)
  const unsigned ts = nw >> 1;
  const unsigned NT = BATCH >> 4;
  f32x4 sums[4], sqs[4];
  #pragma unroll
  for (int mi = 0; mi < 4; ++mi) { sums[mi] = (f32x4){0,0,0,0}; sqs[mi] = (f32x4){0,0,0,0}; }
  const ushort ONE = 0x3F80;
  for (unsigned it = gw >> 1; it < NT; it += ts) {
    const unsigned s = it*16 + m16;
    const int c0 = P.br1[s], c1 = P.tp1[s], c2 = P.br2[s], c3 = P.tp2[s];
    const int c4i = P.sz1[s], c5 = P.en1[s], c6 = P.sz2[s], c7 = P.en2[s];
    const ushort vb0 = bfb(P.ag1[s]*(1.0f/15.0f)), vb1 = bfb(P.so1[s]);
    const ushort vb2 = bfb(P.wt1[s]*0.01f);
    const ushort vb3 = bfb(P.ag2[s]*(1.0f/15.0f)), vb4 = bfb(P.so2[s]);
    const ushort vb5 = bfb(P.wt2[s]*0.01f);
#define INDE(cv, tgt) ((ushort)(((cv) == (tgt)) ? ONE : 0))
    const ushort e0 = INDE(c0, q),     e1 = INDE(c0, 4+q);
    const ushort e2 = INDE(c0, 8+q);
    const ushort e3 = (q == 3) ? ONE : INDE(c0, 12+q);
    const ushort e4 = INDE(c1, q),     e5 = INDE(c1, 4+q);
    const ushort e6 = (q == 0) ? INDE(c1, 8)
                               : ((q == 1) ? vb0 : (q == 2) ? vb1 : vb2);
    const ushort e7 = INDE(c4i, q);
    const ushort f0 = INDE(c2, q),     f1 = INDE(c2, 4+q);
    const ushort f2 = INDE(c2, 8+q),   f3 = INDE(c2, 12+q);
    const ushort f4 = INDE(c3, q),     f5 = INDE(c3, 4+q);
    const ushort f6 = (q == 0) ? INDE(c3, 8)
                               : ((q == 1) ? vb3 : (q == 2) ? vb4 : vb5);
    const ushort f7 = INDE(c5, q);
    const ushort g0 = INDE(c6, q),     g1 = INDE(c7, q);
#undef INDE
    const bf16x8 B0 = mkfrag(pku(e0,e1), pku(e2,e3), pku(e4,e5), pku(e6,e7));
    const bf16x8 B1 = mkfrag(pku(f0,f1), pku(f2,f3), pku(f4,f5), pku(f6,f7));
    const bf16x8 B2 = mkfrag(pku(g0,g1), 0u, 0u, 0u);
    #pragma unroll
    for (int mi = 0; mi < 4; ++mi) {
      const int mt = mt0 + mi;
      f32x4 D = (f32x4){0.f,0.f,0.f,0.f};
      #pragma unroll
      for (int kk = 0; kk < 3; ++kk) {
        const bf16x8 bf = (kk == 0) ? B0 : (kk == 1) ? B1 : B2;
        const bf16x8 ah = ldfrag(Wl + (size_t)(((mt*3+kk)*2+0)*64 + lane)*16);
        D = __builtin_amdgcn_mfma_f32_16x16x32_bf16(ah, bf, D, 0, 0, 0);
        const bf16x8 al = ldfrag(Wl + (size_t)(((mt*3+kk)*2+1)*64 + lane)*16);
        D = __builtin_amdgcn_mfma_f32_16x16x32_bf16(al, bf, D, 0, 0, 0);
      }
      #pragma unroll
      for (int r = 0; r < 4; ++r) {
        sums[mi][r] += D[r];
        sqs[mi][r]   = fmaf(D[r], D[r], sqs[mi][r]);
      }
    }
  }
  #pragma unroll
  for (int d = 1; d <= 8; d <<= 1) {
    #pragma unroll
    for (int mi = 0; mi < 4; ++mi) {
      #pragma unroll
      for (int r = 0; r < 4; ++r) {
        sums[mi][r] += __shfl_xor(sums[mi][r], d, 64);
        sqs[mi][r]  += __shfl_xor(sqs[mi][r],  d, 64);
      }
    }
  }
  if (m16 == 0) {
    #pragma unroll
    for (int mi = 0; mi < 4; ++mi) {
      #pragma unroll
      for (int r = 0; r < 4; ++r) {
        const int ch = 16*(mt0 + mi) + 4*q + r;
        atomicAdd(&sred[ch], sums[mi][r]);
        atomicAdd(&sred[128+ch], sqs[mi][r]);
      }
    }
  }
  __syncthreads();
  if (threadIdx.x < 128) {
    float* stat = (float*)((char*)P.ws + OFF_STATS) + (size_t)threadIdx.x*16;
    atomicAdd(stat,     sred[threadIdx.x]);
    atomicAdd(stat + 8, sred[128+threadIdx.x]);
  }
}

// BN1 stats by direct encode (FALLBACK path only)
__global__ __launch_bounds__(512) void k_stats1(Ptrs P) {
  __shared__ __align__(16) float Tl[60*TSTR];
  __shared__ float sred[256];
  for (int i = threadIdx.x; i < 60*TSTR; i += 512) Tl[i] = P.ws[i];
  if (threadIdx.x < 256) sred[threadIdx.x] = 0.f;
  __syncthreads();
  const int lane = threadIdx.x & 63;
  const int q = lane >> 4, m16 = lane & 15;
  const float* contT = P.ws;
  const unsigned gw = (blockIdx.x*512 + threadIdx.x) >> 6;
  const unsigned nw = (gridDim.x*512) >> 6;
  const int kk = gw & 3;
  const int c = kk*32 + 8*q;
  const unsigned NT = BATCH >> 4;
  unsigned it = gw >> 2;
  const unsigned ts = nw >> 2;
  float4 sa = make_float4(0,0,0,0), sb = sa, qa = sa, qb = sa;
  bool active = it < NT;
  int rb[8]; float v[6];
  if (active) load_rb(P, it*16 + m16, rb, v);
  while (active) {
    const unsigned itn = it + ts;
    const bool more = itn < NT;
    int rbn[8]; float vn[6];
    if (more) load_rb(P, itn*16 + m16, rbn, vn);
    const float4 xa = gather4(Tl, contT, rb, v, c);
    const float4 xb = gather4(Tl, contT, rb, v, c + 4);
    add4(sa, xa); add4(sb, xb);
    qa.x = fmaf(xa.x, xa.x, qa.x); qa.y = fmaf(xa.y, xa.y, qa.y);
    qa.z = fmaf(xa.z, xa.z, qa.z); qa.w = fmaf(xa.w, xa.w, qa.w);
    qb.x = fmaf(xb.x, xb.x, qb.x); qb.y = fmaf(xb.y, xb.y, qb.y);
    qb.z = fmaf(xb.z, xb.z, qb.z); qb.w = fmaf(xb.w, xb.w, qb.w);
    if (!more) break;
    #pragma unroll
    for (int i = 0; i < 8; ++i) rb[i] = rbn[i];
    #pragma unroll
    for (int i = 0; i < 6; ++i) v[i] = vn[i];
    it = itn;
  }
  #pragma unroll
  for (int d = 1; d <= 8; d <<= 1) {
    sa.x += __shfl_xor(sa.x, d, 64); sa.y += __shfl_xor(sa.y, d, 64);
    sa.z += __shfl_xor(sa.z, d, 64); sa.w += __shfl_xor(sa.w, d, 64);
    sb.x += __shfl_xor(sb.x, d, 64); sb.y += __shfl_xor(sb.y, d, 64);
    sb.z += __shfl_xor(sb.z, d, 64); sb.w += __shfl_xor(sb.w, d, 64);
    qa.x += __shfl_xor(qa.x, d, 64); qa.y += __shfl_xor(qa.y, d, 64);
    qa.z += __shfl_xor(qa.z, d, 64); qa.w += __shfl_xor(qa.w, d, 64);
    qb.x += __shfl_xor(qb.x, d, 64); qb.y += __shfl_xor(qb.y, d, 64);
    qb.z += __shfl_xor(qb.z, d, 64); qb.w += __shfl_xor(qb.w, d, 64);
  }
  if (m16 == 0) {
    atomicAdd(&sred[c+0], sa.x); atomicAdd(&sred[c+1], sa.y);
    atomicAdd(&sred[c+2], sa.z); atomicAdd(&sred[c+3], sa.w);
    atomicAdd(&sred[c+4], sb.x); atomicAdd(&sred[c+5], sb.y);
    atomicAdd(&sred[c+6], sb.z); atomicAdd(&sred[c+7], sb.w);
    atomicAdd(&sred[128+c+0], qa.x); atomicAdd(&sred[128+c+1], qa.y);
    atomicAdd(&sred[128+c+2], qa.z); atomicAdd(&sred[128+c+3], qa.w);
    atomicAdd(&sred[128+c+4], qb.x); atomicAdd(&sred[128+c+5], qb.y);
    atomicAdd(&sred[128+c+6], qb.z); atomicAdd(&sred[128+c+7], qb.w);
  }
  __syncthreads();
  if (threadIdx.x < 128) {
    float* stat = (float*)((char*)P.ws + OFF_STATS) + (size_t)threadIdx.x*16;
    atomicAdd(stat,     sred[threadIdx.x]);
    atomicAdd(stat + 8, sred[128+threadIdx.x]);
  }
}

// fallback-path finalize
__global__ void k_finalize(Ptrs P, int nch, int entry0, int pofs,
                           const float* g, const float* be) {
  const int c = threadIdx.x;
  if (c >= nch) return;
  const float* stat = (const float*)((const char*)P.ws + OFF_STATS) + (size_t)(entry0 + c)*16;
  const float mean = stat[0] * INV_B;
  const float var  = stat[8] * INV_B - mean*mean;
  const float inv  = 1.0f / sqrtf(var + EPSBN);
  const float scale = g[c] * inv;
  float* params = (float*)((char*)P.ws + OFF_PARAMS);
  params[pofs + c]       = scale;
  params[pofs + nch + c] = be[c] - mean * scale;
}

// Layer2 MFMA, LEAN (round-9 proven): in-kernel BN1 finalize into LDS bn[].
__global__ __launch_bounds__(512) void k_l2m(Ptrs P) {
  __shared__ __align__(16) float Tl[60*TSTR];
  __shared__ __align__(16) float bn[256];   // sc1[0..127], sh1[128..255]
  for (int i = threadIdx.x; i < 60*TSTR; i += 512) Tl[i] = P.ws[i];
  if (threadIdx.x < 128) {
    const float* stat = (const float*)((const char*)P.ws + OFF_STATS) + (size_t)threadIdx.x*16;
    const float mean = stat[0] * INV_B;
    const float var  = stat[8] * INV_B - mean*mean;
    const float scale = P.g1[threadIdx.x] / sqrtf(var + EPSBN);
    bn[threadIdx.x]       = scale;
    bn[128 + threadIdx.x] = P.be1[threadIdx.x] - mean * scale;
  }
  __syncthreads();
  const float* contT = P.ws;
  const int lane = threadIdx.x & 63;
  const int q = lane >> 4, m16 = lane & 15;
  const char* w2fB = (const char*)P.ws + OFF_W2F;
  char* x2B = (char*)P.ws + OFF_X2;
  const unsigned nw = (gridDim.x*512) >> 6;
  const unsigned NT = BATCH >> 4;
  unsigned it = (blockIdx.x*512 + threadIdx.x) >> 6;
  if (it >= NT) return;
  SIdx cur = load_idx(P, it*16 + m16);
  while (true) {
    const unsigned itn = it + nw;
    const bool more = itn < NT;
    SIdx nxt;
    if (more) nxt = load_idx(P, itn*16 + m16);   // prefetch next tile's indices
    const unsigned s = it*16 + m16;
    int rb[8];
    #pragma unroll
    for (int i = 0; i < 8; ++i) rb[i] = cur.r[i]*TSTR;
    f32x4 D[4];
    #pragma unroll
    for (int mt = 0; mt < 4; ++mt) {
      const float4 b = ld4(P.b2 + 16*mt + 4*q);
      D[mt][0] = b.x; D[mt][1] = b.y; D[mt][2] = b.z; D[mt][3] = b.w;
    }
    #pragma unroll
    for (int kk = 0; kk < 4; ++kk) {
      const int c = kk*32 + 8*q;
      const float4 xa = gather4(Tl, contT, rb, cur.v, c);
      const float4 xb = gather4(Tl, contT, rb, cur.v, c + 4);
      const float4 sca = ld4(bn + c), sha = ld4(bn + 128 + c);
      const float4 scb = ld4(bn + c + 4), shb = ld4(bn + 128 + c + 4);
      const float h0 = fmaxf(fmaf(xa.x, sca.x, sha.x), 0.f);
      const float h1 = fmaxf(fmaf(xa.y, sca.y, sha.y), 0.f);
      const float h2 = fmaxf(fmaf(xa.z, sca.z, sha.z), 0.f);
      const float h3 = fmaxf(fmaf(xa.w, sca.w, sha.w), 0.f);
      const float h4 = fmaxf(fmaf(xb.x, scb.x, shb.x), 0.f);
      const float h5 = fmaxf(fmaf(xb.y, scb.y, shb.y), 0.f);
      const float h6 = fmaxf(fmaf(xb.z, scb.z, shb.z), 0.f);
      const float h7 = fmaxf(fmaf(xb.w, scb.w, shb.w), 0.f);
      const bf16x8 bf = mkfrag(pk2(h0,h1), pk2(h2,h3), pk2(h4,h5), pk2(h6,h7));
      #pragma unroll
      for (int mt = 0; mt < 4; ++mt) {
        const bf16x8 af = ldfrag(w2fB + (size_t)((mt*4+kk)*64 + lane)*16);
        D[mt] = __builtin_amdgcn_mfma_f32_16x16x32_bf16(af, bf, D[mt], 0, 0, 0);
      }
    }
    #pragma unroll
    for (int mt = 0; mt < 4; ++mt) {
      const uint lo = pk2(D[mt][0], D[mt][1]);
      const uint hi = pk2(D[mt][2], D[mt][3]);
      *reinterpret_cast<uint2*>(x2B + (size_t)s*128 + (16*mt + 4*q)*2) = make_uint2(lo, hi);
    }
    if (!more) break;
    cur = nxt; it = itn;
  }
}

// BN2 stats from stored bf16 x2 (round-9)
__global__ __launch_bounds__(256) void k_stats2(Ptrs P) {
  const uint* x2u = (const uint*)((const char*)P.ws + OFF_X2);
  const int pid = threadIdx.x & 31;
  const int lane = threadIdx.x & 63;
  const int w = threadIdx.x >> 6;
  float slo = 0.f, shi = 0.f, qlo = 0.f, qhi = 0.f;
  const unsigned r0 = blockIdx.x*8 + (threadIdx.x >> 5);
  const unsigned rs = gridDim.x*8;
  #pragma unroll 4
  for (unsigned r = r0; r < BATCH; r += rs) {
    const uint u = x2u[(size_t)r*32 + pid];
    const float lo = bflo(u), hi = bfhi(u);
    slo += lo; shi += hi;
    qlo = fmaf(lo, lo, qlo); qhi = fmaf(hi, hi, qhi);
  }
  slo += __shfl_xor(slo, 32, 64); shi += __shfl_xor(shi, 32, 64);
  qlo += __shfl_xor(qlo, 32, 64); qhi += __shfl_xor(qhi, 32, 64);
  __shared__ float red[512];
  if (lane < 32) {
    red[w*64 + 2*pid]       = slo; red[w*64 + 2*pid + 1]       = shi;
    red[256 + w*64 + 2*pid] = qlo; red[256 + w*64 + 2*pid + 1] = qhi;
  }
  __syncthreads();
  if (threadIdx.x < 64) {
    const int c = threadIdx.x;
    const float s  = red[c] + red[64+c] + red[128+c] + red[192+c];
    const float qq = red[256+c] + red[320+c] + red[384+c] + red[448+c];
    float* stat = (float*)((char*)P.ws + OFF_STATS) + (size_t)(128 + c)*16;
    atomicAdd(stat, s); atomicAdd(stat + 8, qq);
  }
}

// Layer3 MFMA (round-9): in-kernel BN2 finalize; x2 prefetch; optional dense x3
__global__ __launch_bounds__(256) void k_l3m(Ptrs P, int dense) {
  __shared__ __align__(16) float bn[128];
  if (threadIdx.x < 64) {
    const float* stat = (const float*)((const char*)P.ws + OFF_STATS) + (size_t)(128 + threadIdx.x)*16;
    const float mean = stat[0] * INV_B;
    const float var  = stat[8] * INV_B - mean*mean;
    const float scale = P.g2[threadIdx.x] / sqrtf(var + EPSBN);
    bn[threadIdx.x]      = scale;
    bn[64 + threadIdx.x] = P.be2[threadIdx.x] - mean * scale;
  }
  __syncthreads();
  const int lane = threadIdx.x & 63;
  const int q = lane >> 4, m16 = lane & 15;
  const char* w3fB = (const char*)P.ws + OFF_W3F;
  const char* xB = (const char*)P.ws + OFF_X2;
  char* x3B = dense ? ((char*)P.ws + OFF_X3D) : ((char*)P.ws + OFF_X2);
  const size_t x3str = dense ? 64 : 128;
  const unsigned nw = (gridDim.x*256) >> 6;
  const unsigned NT = BATCH >> 4;
  unsigned it = (blockIdx.x*256 + threadIdx.x) >> 6;
  if (it >= NT) return;
  unsigned s = it*16 + m16;
  uint4 u0 = *reinterpret_cast<const uint4*>(xB + (size_t)s*128 + q*16);
  uint4 u1 = *reinterpret_cast<const uint4*>(xB + (size_t)s*128 + 64 + q*16);
  while (true) {
    const unsigned itn = it + nw;
    const bool more = itn < NT;
    uint4 n0, n1;
    if (more) {
      const unsigned sn = itn*16 + m16;
      n0 = *reinterpret_cast<const uint4*>(xB + (size_t)sn*128 + q*16);
      n1 = *reinterpret_cast<const uint4*>(xB + (size_t)sn*128 + 64 + q*16);
    }
    f32x4 D[2];
    #pragma unroll
    for (int mt = 0; mt < 2; ++mt) {
      const float4 b = ld4(P.b3 + 16*mt + 4*q);
      D[mt][0] = b.x; D[mt][1] = b.y; D[mt][2] = b.z; D[mt][3] = b.w;
    }
    #pragma unroll
    for (int kk = 0; kk < 2; ++kk) {
      const uint4 u = (kk == 0) ? u0 : u1;
      const int c = kk*32 + 8*q;
      const float4 scA = ld4(bn + c), shA = ld4(bn + 64 + c);
      const float4 scB = ld4(bn + c + 4), shB = ld4(bn + 64 + c + 4);
      const uint w[4] = {u.x,u.y,u.z,u.w};
      const float h0 = fmaxf(fmaf(bflo(w[0]), scA.x, shA.x), 0.f);
      const float h1 = fmaxf(fmaf(bfhi(w[0]), scA.y, shA.y), 0.f);
      const float h2 = fmaxf(fmaf(bflo(w[1]), scA.z, shA.z), 0.f);
      const float h3 = fmaxf(fmaf(bfhi(w[1]), scA.w, shA.w), 0.f);
      const float h4 = fmaxf(fmaf(bflo(w[2]), scB.x, shB.x), 0.f);
      const float h5 = fmaxf(fmaf(bfhi(w[2]), scB.y, shB.y), 0.f);
      const float h6 = fmaxf(fmaf(bflo(w[3]), scB.z, shB.z), 0.f);
      const float h7 = fmaxf(fmaf(bfhi(w[3]), scB.w, shB.w), 0.f);
      const bf16x8 bf = mkfrag(pk2(h0,h1), pk2(h2,h3), pk2(h4,h5), pk2(h6,h7));
      #pragma unroll
      for (int mt = 0; mt < 2; ++mt) {
        const bf16x8 af = ldfrag(w3fB + (size_t)((mt*2+kk)*64 + lane)*16);
        D[mt] = __builtin_amdgcn_mfma_f32_16x16x32_bf16(af, bf, D[mt], 0, 0, 0);
      }
    }
    #pragma unroll
    for (int mt = 0; mt < 2; ++mt) {
      const uint lo = pk2(D[mt][0], D[mt][1]);
      const uint hi = pk2(D[mt][2], D[mt][3]);
      *reinterpret_cast<uint2*>(x3B + (size_t)s*x3str + (16*mt + 4*q)*2) = make_uint2(lo, hi);
    }
    if (!more) break;
    u0 = n0; u1 = n1; it = itn; s = it*16 + m16;
  }
}

// BN3 stats (round-9)
__global__ __launch_bounds__(256) void k_stats3(Ptrs P, int dense) {
  const uint* xu = dense ? (const uint*)((const char*)P.ws + OFF_X3D)
                         : (const uint*)((const char*)P.ws + OFF_X2);
  const unsigned rstr = dense ? 16 : 32;
  const int pid = threadIdx.x & 15;
  const int lane = threadIdx.x & 63;
  const int w = threadIdx.x >> 6;
  float slo = 0.f, shi = 0.f, qlo = 0.f, qhi = 0.f;
  const unsigned r0 = blockIdx.x*16 + (threadIdx.x >> 4);
  const unsigned rs = gridDim.x*16;
  #pragma unroll 4
  for (unsigned r = r0; r < BATCH; r += rs) {
    const uint u = xu[(size_t)r*rstr + pid];
    const float lo = bflo(u), hi = bfhi(u);
    slo += lo; shi += hi;
    qlo = fmaf(lo, lo, qlo); qhi = fmaf(hi, hi, qhi);
  }
  #pragma unroll
  for (int d = 16; d <= 32; d <<= 1) {
    slo += __shfl_xor(slo, d, 64); shi += __shfl_xor(shi, d, 64);
    qlo += __shfl_xor(qlo, d, 64); qhi += __shfl_xor(qhi, d, 64);
  }
  __shared__ float red[256];
  if (lane < 16) {
    red[w*32 + 2*pid]       = slo; red[w*32 + 2*pid + 1]       = shi;
    red[128 + w*32 + 2*pid] = qlo; red[128 + w*32 + 2*pid + 1] = qhi;
  }
  __syncthreads();
  if (threadIdx.x < 32) {
    const int c = threadIdx.x;
    const float s  = red[c] + red[32+c] + red[64+c] + red[96+c];
    const float qq = red[128+c] + red[160+c] + red[192+c] + red[224+c];
    float* stat = (float*)((char*)P.ws + OFF_STATS) + (size_t)(192 + c)*16;
    atomicAdd(stat, s); atomicAdd(stat + 8, qq);
  }
}

// Layer4 (round-9)
__global__ __launch_bounds__(256) void k_l4n(Ptrs P, int dense) {
  __shared__ float bn[64];
  if (threadIdx.x < 32) {
    const float* stat = (const float*)((const char*)P.ws + OFF_STATS) + (size_t)(192 + threadIdx.x)*16;
    const float mean = stat[0] * INV_B;
    const float var  = stat[8] * INV_B - mean*mean;
    const float scale = P.g3[threadIdx.x] / sqrtf(var + EPSBN);
    bn[threadIdx.x]      = scale;
    bn[32 + threadIdx.x] = P.be3[threadIdx.x] - mean * scale;
  }
  __syncthreads();
  const float* sc3 = bn, *sh3 = bn + 32;
  const char* xB = dense ? ((const char*)P.ws + OFF_X3D) : ((const char*)P.ws + OFF_X2);
  const size_t xstr = dense ? 64 : 128;
  const unsigned stride = gridDim.x * 256;
  for (unsigned s = blockIdx.x*256 + threadIdx.x; s < BATCH; s += stride) {
    float z = P.b4[0];
    #pragma unroll
    for (int c16 = 0; c16 < 4; ++c16) {
      const uint4 u = *reinterpret_cast<const uint4*>(xB + (size_t)s*xstr + c16*16);
      const uint w[4] = {u.x,u.y,u.z,u.w};
      #pragma unroll
      for (int j = 0; j < 4; ++j) {
        const int ch = c16*8 + 2*j;
        const float hlo = fmaxf(fmaf(bflo(w[j]), sc3[ch],   sh3[ch]),   0.f);
        const float hhi = fmaxf(fmaf(bfhi(w[j]), sc3[ch+1], sh3[ch+1]), 0.f);
        z = fmaf(hlo, P.W4[ch], z);
        z = fmaf(hhi, P.W4[ch+1], z);
      }
    }
    P.out[s] = 1.0f / (1.0f + __expf(-z));
  }
}

// -------- fallback (small ws): recompute path (round-9) --------
__global__ __launch_bounds__(256) void k_l2r(Ptrs P) {
  __shared__ __align__(16) float Tl[68*TSTR];
  __shared__ float red[512];
  const float* params = (const float*)((const char*)P.ws + OFF_PARAMS);
  stage_tab(P.ws, params, Tl, true);
  const int lane = threadIdx.x & 63;
  float4 sums[16], sqs[16];
  #pragma unroll
  for (int j4 = 0; j4 < 16; ++j4) {
    sums[j4] = make_float4(0.f,0.f,0.f,0.f);
    sqs[j4]  = make_float4(0.f,0.f,0.f,0.f);
  }
  const unsigned stride = gridDim.x * 256;
  for (unsigned s = blockIdx.x*256 + threadIdx.x; s < BATCH; s += stride) {
    int rb[8]; float v[6];
    load_rb(P, s, rb, v);
    float4 acc[16];
    x2_from_lds(Tl, rb, v, P.W2, P.b2, acc);
    #pragma unroll
    for (int j4 = 0; j4 < 16; ++j4) {
      add4(sums[j4], acc[j4]);
      sqs[j4].x = fmaf(acc[j4].x, acc[j4].x, sqs[j4].x);
      sqs[j4].y = fmaf(acc[j4].y, acc[j4].y, sqs[j4].y);
      sqs[j4].z = fmaf(acc[j4].z, acc[j4].z, sqs[j4].z);
      sqs[j4].w = fmaf(acc[j4].w, acc[j4].w, sqs[j4].w);
    }
  }
  const float psum = bfly64_from<false>(sums, lane);
  const float psq  = bfly64_from<false>(sqs,  lane);
  red[threadIdx.x] = psum; red[256 + threadIdx.x] = psq;
  __syncthreads();
  const int t = threadIdx.x;
  if (t < 64) {
    const float s0 = red[t] + red[t+64] + red[t+128] + red[t+192];
    const float q0 = red[256+t] + red[256+t+64] + red[256+t+128] + red[256+t+192];
    float* stat = (float*)((char*)P.ws + OFF_STATS) + (size_t)(128 + t)*16;
    atomicAdd(stat, s0); atomicAdd(stat + 8, q0);
  }
}

__global__ __launch_bounds__(256) void k_l3_rec(Ptrs P) {
  __shared__ __align__(16) float Tl[68*TSTR];
  __shared__ float red[512];
  const float* params = (const float*)((const char*)P.ws + OFF_PARAMS);
  stage_tab(P.ws, params, Tl, true);
  const float* sc2 = params + 256, *sh2 = params + 320;
  const int lane = threadIdx.x & 63;
  float4 sums3[8], sqs3[8];
  #pragma unroll
  for (int j4 = 0; j4 < 8; ++j4) {
    sums3[j4] = make_float4(0.f,0.f,0.f,0.f);
    sqs3[j4]  = make_float4(0.f,0.f,0.f,0.f);
  }
  const unsigned stride = gridDim.x * 256;
  for (unsigned s = blockIdx.x*256 + threadIdx.x; s < BATCH; s += stride) {
    int rb[8]; float v[6];
    load_rb(P, s, rb, v);
    float4 acc2[16];
    x2_from_lds(Tl, rb, v, P.W2, P.b2, acc2);
    float4 acc3[8];
    x3_from_acc2(acc2, P, sc2, sh2, acc3);
    #pragma unroll
    for (int j4 = 0; j4 < 8; ++j4) {
      add4(sums3[j4], acc3[j4]);
      sqs3[j4].x = fmaf(acc3[j4].x, acc3[j4].x, sqs3[j4].x);
      sqs3[j4].y = fmaf(acc3[j4].y, acc3[j4].y, sqs3[j4].y);
      sqs3[j4].z = fmaf(acc3[j4].z, acc3[j4].z, sqs3[j4].z);
      sqs3[j4].w = fmaf(acc3[j4].w, acc3[j4].w, sqs3[j4].w);
    }
  }
  const float psum = bfly32_from<false>(sums3, lane);
  const float psq  = bfly32_from<false>(sqs3,  lane);
  red[threadIdx.x] = psum; red[256 + threadIdx.x] = psq;
  __syncthreads();
  const int t = threadIdx.x;
  if (t < 32) {
    const float s0 = red[t] + red[t+64] + red[t+128] + red[t+192];
    const float q0 = red[256+t] + red[256+t+64] + red[256+t+128] + red[256+t+192];
    float* stat = (float*)((char*)P.ws + OFF_STATS) + (size_t)(192 + t)*16;
    atomicAdd(stat, s0); atomicAdd(stat + 8, q0);
  }
}

__global__ __launch_bounds__(256) void k_l4_rec(Ptrs P) {
  __shared__ __align__(16) float Tl[68*TSTR];
  const float* params = (const float*)((const char*)P.ws + OFF_PARAMS);
  stage_tab(P.ws, params, Tl, true);
  const float* sc2 = params + 256, *sh2 = params + 320;
  const float* sc3 = params + 384, *sh3 = params + 416;
  const unsigned stride = gridDim.x * 256;
  for (unsigned s = blockIdx.x*256 + threadIdx.x; s < BATCH; s += stride) {
    int rb[8]; float v[6];
    load_rb(P, s, rb, v);
    float4 acc2[16];
    x2_from_lds(Tl, rb, v, P.W2, P.b2, acc2);
    float4 acc3[8];
    x3_from_acc2(acc2, P, sc2, sh2, acc3);
    float z = P.b4[0];
    #pragma unroll
    for (int k4 = 0; k4 < 8; ++k4) {
      const float4 a = acc3[k4];
      const float4 sc = ld4(sc3 + k4*4), sh = ld4(sh3 + k4*4);
      z = fmaf(fmaxf(fmaf(a.x, sc.x, sh.x), 0.0f), P.W4[k4*4+0], z);
      z = fmaf(fmaxf(fmaf(a.y, sc.y, sh.y), 0.0f), P.W4[k4*4+1], z);
      z = fmaf(fmaxf(fmaf(a.z, sc.z, sh.z), 0.0f), P.W4[k4*4+2], z);
      z = fmaf(fmaxf(fmaf(a.w, sc.w, sh.w), 0.0f), P.W4[k4*4+3], z);
    }
    P.out[s] = 1.0f / (1.0f + __expf(-z));
  }
}

// ---------------- host ----------------

extern "C" void kernel_launch(void* const* d_in, const int* in_sizes, int n_in,
                              void* d_out, int out_size, void* d_ws, size_t ws_size,
                              hipStream_t stream) {
  Ptrs P;
  P.br1 = (const int*)d_in[0];  P.sz1 = (const int*)d_in[1];
  P.en1 = (const int*)d_in[2];  P.tp1 = (const int*)d_in[3];
  P.ag1 = (const float*)d_in[4]; P.so1 = (const float*)d_in[5]; P.wt1 = (const float*)d_in[6];
  P.br2 = (const int*)d_in[7];  P.sz2 = (const int*)d_in[8];
  P.en2 = (const int*)d_in[9];  P.tp2 = (const int*)d_in[10];
  P.ag2 = (const float*)d_in[11]; P.so2 = (const float*)d_in[12]; P.wt2 = (const float*)d_in[13];
  P.bemb = (const float*)d_in[14]; P.temb = (const float*)d_in[15];
  P.W1 = (const float*)d_in[16]; P.b1 = (const float*)d_in[17];
  P.g1 = (const float*)d_in[18]; P.be1 = (const float*)d_in[19];
  P.W2 = (const float*)d_in[20]; P.b2 = (const float*)d_in[21];
  P.g2 = (const float*)d_in[22]; P.be2 = (const float*)d_in[23];
  P.W3 = (const float*)d_in[24]; P.b3 = (const float*)d_in[25];
  P.g3 = (const float*)d_in[26]; P.be3 = (const float*)d_in[27];
  P.W4 = (const float*)d_in[28]; P.b4 = (const float*)d_in[29];
  P.ws = (float*)d_ws; P.out = (float*)d_out;

  const bool t1 = ws_size >= T1_NEED;
  const int dense = (ws_size >= T2_NEED) ? 1 : 0;

  hipLaunchKernelGGL(k_prep, dim3(1), dim3(256), 0, stream, P);
  if (t1) {
    hipLaunchKernelGGL(k_stats1m, dim3(1024), dim3(512), 0, stream, P);
    hipLaunchKernelGGL(k_l2m, dim3(1024), dim3(512), 0, stream, P);
    hipLaunchKernelGGL(k_stats2, dim3(1024), dim3(256), 0, stream, P);
    hipLaunchKernelGGL(k_l3m, dim3(2048), dim3(256), 0, stream, P, dense);
    hipLaunchKernelGGL(k_stats3, dim3(1024), dim3(256), 0, stream, P, dense);
    hipLaunchKernelGGL(k_l4n, dim3(2048), dim3(256), 0, stream, P, dense);
  } else {
    hipLaunchKernelGGL(k_stats1, dim3(1024), dim3(512), 0, stream, P);
    hipLaunchKernelGGL(k_finalize, dim3(1), dim3(128), 0, stream, P, 128, 0, 0, P.g1, P.be1);
    hipLaunchKernelGGL(k_l2r, dim3(1024), dim3(256), 0, stream, P);
    hipLaunchKernelGGL(k_finalize, dim3(1), dim3(64), 0, stream, P, 64, 128, 256, P.g2, P.be2);
    hipLaunchKernelGGL(k_l3_rec, dim3(1024), dim3(256), 0, stream, P);
    hipLaunchKernelGGL(k_finalize, dim3(1), dim3(32), 0, stream, P, 32, 192, 384, P.g3, P.be3);
    hipLaunchKernelGGL(k_l4_rec, dim3(2048), dim3(256), 0, stream, P);
  }
}